// Round 1
// baseline (152.342 us; speedup 1.0000x reference)
//
#include <hip/hip_runtime.h>

#define NB 32
#define HH 36
#define WWIM 36
#define DD 512
#define KK 64
#define RH 12
#define RW 12
#define NR 9
#define PP 144
#define EPSF 1e-12f

// ---------------------------------------------------------------------------
// K1: per (n, region, pixel-half) compute s = x·W (inner D=512), softmax over
// K=64, write a[n,r,p,k] to workspace.
// Block: 256 threads = 4 waves; wave handles 18 pixels (9 per lane-half);
// lane: kt = lane&31, handles k = kt and kt+32 for its 9 pixels.
// ---------------------------------------------------------------------------
__global__ __launch_bounds__(256) void k1_assign(const float* __restrict__ x,
                                                 const float* __restrict__ Wc,
                                                 float* __restrict__ a_ws) {
  int b = blockIdx.x;            // 576 = 32*9*2
  int n = b / 18;
  int rem = b % 18;
  int r = rem / 2;
  int ph = rem % 2;
  int jy = r / 3, ix = r % 3;
  int y1 = jy * RH, x1 = ix * RW;
  int p0 = ph * 72;

  __shared__ float xs[72 * 68];   // [72][68] (+4 pad keeps float4 align, spreads banks)
  __shared__ float ws[64 * 64];   // W chunk [64 d][64 k]

  int t = threadIdx.x;
  int lane = t & 63;
  int wave = t >> 6;
  int kt = lane & 31;
  int sub = lane >> 5;
  int pbase = wave * 18 + sub * 9;   // local pixel base within the 72-half

  float acc0[9], acc1[9];
#pragma unroll
  for (int i = 0; i < 9; ++i) { acc0[i] = 0.f; acc1[i] = 0.f; }

  for (int d0 = 0; d0 < DD; d0 += 64) {
    // stage x tile [72][64] -> xs (float4 loads, coalesced 16 lanes/row)
    for (int f = t; f < 72 * 16; f += 256) {
      int p = f >> 4, q = f & 15;
      int preg = p0 + p;
      int gy = y1 + preg / 12, gx = x1 + preg % 12;
      const float4 v = *reinterpret_cast<const float4*>(
          x + (((size_t)n * HH + gy) * WWIM + gx) * DD + d0 + q * 4);
      *reinterpret_cast<float4*>(xs + p * 68 + q * 4) = v;
    }
    // stage W chunk [64][64]: contiguous 4096 floats at d0*64
    {
      const float4* src = reinterpret_cast<const float4*>(Wc + d0 * 64);
      float4* dst = reinterpret_cast<float4*>(ws);
      for (int f = t; f < 1024; f += 256) dst[f] = src[f];
    }
    __syncthreads();

#pragma unroll 2
    for (int d4 = 0; d4 < 16; ++d4) {
      float4 xv[9];
#pragma unroll
      for (int i = 0; i < 9; ++i)
        xv[i] = *reinterpret_cast<const float4*>(xs + (pbase + i) * 68 + d4 * 4);
#pragma unroll
      for (int j = 0; j < 4; ++j) {
        int d = d4 * 4 + j;
        float w0 = ws[d * 64 + kt];
        float w1 = ws[d * 64 + kt + 32];
#pragma unroll
        for (int i = 0; i < 9; ++i) {
          float xx = (j == 0) ? xv[i].x : (j == 1) ? xv[i].y
                   : (j == 2) ? xv[i].z : xv[i].w;
          acc0[i] = fmaf(xx, w0, acc0[i]);
          acc1[i] = fmaf(xx, w1, acc1[i]);
        }
      }
    }
    __syncthreads();
  }

  // softmax over k=64 per pixel: butterfly across the 32 lanes of each half
  // (each lane holds k=kt and kt+32; masks <=16 stay within the half).
  size_t abase = ((size_t)n * NR + r) * PP * KK;
#pragma unroll
  for (int i = 0; i < 9; ++i) {
    float m = fmaxf(acc0[i], acc1[i]);
#pragma unroll
    for (int off = 16; off >= 1; off >>= 1) m = fmaxf(m, __shfl_xor(m, off));
    float e0 = __expf(acc0[i] - m);
    float e1 = __expf(acc1[i] - m);
    float s = e0 + e1;
#pragma unroll
    for (int off = 16; off >= 1; off >>= 1) s += __shfl_xor(s, off);
    float inv = 1.0f / s;
    int p = p0 + pbase + i;
    a_ws[abase + (size_t)p * KK + kt]      = e0 * inv;
    a_ws[abase + (size_t)p * KK + kt + 32] = e1 * inv;
  }
}

// ---------------------------------------------------------------------------
// K2: per (n, region, d-chunk of 128) compute
//   v[d,k] = sum_p x[p,d]*a[p,k] - C[d,k]*asum[k]
// write raw v to d_out, accumulate per-k column-norm^2 via one atomicAdd/k.
// Thread: kt = t&31, half = (t>>5)&1, wave = t>>6; owns 16 d x 2 k.
// ---------------------------------------------------------------------------
__global__ __launch_bounds__(256) void k2_vlad(const float* __restrict__ x,
                                               const float* __restrict__ C,
                                               const float* __restrict__ a_ws,
                                               float* __restrict__ out,
                                               float* __restrict__ colnorm) {
  int b = blockIdx.x;              // 1152 = 32*9*4
  int n = b / 36;
  int rem = b % 36;
  int r = rem / 4;
  int dc = rem % 4;
  int d0 = dc * 128;
  int jy = r / 3, ix = r % 3;
  int y1 = jy * RH, x1 = ix * RW;

  __shared__ float xs[36 * 128];
  __shared__ float as[36 * 64];
  __shared__ float red[512];

  int t = threadIdx.x;
  int kt = t & 31;
  int half = (t >> 5) & 1;
  int wave = t >> 6;
  int dbase = wave * 32 + half * 16;   // this thread's 16 d's start here (within chunk)

  float acc0[16], acc1[16];
#pragma unroll
  for (int i = 0; i < 16; ++i) { acc0[i] = 0.f; acc1[i] = 0.f; }
  float asum0 = 0.f, asum1 = 0.f;

  size_t abase = ((size_t)n * NR + r) * PP * KK;

  for (int pc = 0; pc < 4; ++pc) {
    for (int f = t; f < 36 * 16; f += 256) {     // a chunk [36][64]
      int p = f >> 4, q = f & 15;
      const float4 v = *reinterpret_cast<const float4*>(
          a_ws + abase + (size_t)(pc * 36 + p) * KK + q * 4);
      *reinterpret_cast<float4*>(as + p * 64 + q * 4) = v;
    }
    for (int f = t; f < 36 * 32; f += 256) {     // x chunk [36][128]
      int p = f >> 5, q = f & 31;
      int preg = pc * 36 + p;
      int gy = y1 + preg / 12, gx = x1 + preg % 12;
      const float4 v = *reinterpret_cast<const float4*>(
          x + (((size_t)n * HH + gy) * WWIM + gx) * DD + d0 + q * 4);
      *reinterpret_cast<float4*>(xs + p * 128 + q * 4) = v;
    }
    __syncthreads();

#pragma unroll 4
    for (int p = 0; p < 36; ++p) {
      float a0 = as[p * 64 + kt];
      float a1 = as[p * 64 + kt + 32];
      asum0 += a0; asum1 += a1;
      const float4* xp = reinterpret_cast<const float4*>(xs + p * 128 + dbase);
#pragma unroll
      for (int q = 0; q < 4; ++q) {
        float4 xv = xp[q];
        acc0[q*4+0] = fmaf(xv.x, a0, acc0[q*4+0]); acc1[q*4+0] = fmaf(xv.x, a1, acc1[q*4+0]);
        acc0[q*4+1] = fmaf(xv.y, a0, acc0[q*4+1]); acc1[q*4+1] = fmaf(xv.y, a1, acc1[q*4+1]);
        acc0[q*4+2] = fmaf(xv.z, a0, acc0[q*4+2]); acc1[q*4+2] = fmaf(xv.z, a1, acc1[q*4+2]);
        acc0[q*4+3] = fmaf(xv.w, a0, acc0[q*4+3]); acc1[q*4+3] = fmaf(xv.w, a1, acc1[q*4+3]);
      }
    }
    __syncthreads();
  }

  size_t obase = ((size_t)n * NR + r) * DD * KK;
  float cn0 = 0.f, cn1 = 0.f;
#pragma unroll
  for (int i = 0; i < 16; ++i) {
    int d = d0 + dbase + i;
    float c0 = C[d * KK + kt];
    float c1 = C[d * KK + kt + 32];
    float v0 = acc0[i] - c0 * asum0;
    float v1 = acc1[i] - c1 * asum1;
    out[obase + (size_t)d * KK + kt]      = v0;
    out[obase + (size_t)d * KK + kt + 32] = v1;
    cn0 += v0 * v0;
    cn1 += v1 * v1;
  }

  red[t] = cn0; red[256 + t] = cn1;
  __syncthreads();
  if (t < 64) {
    float s = 0.f;
    if (t < 32) {
#pragma unroll
      for (int j = 0; j < 8; ++j) s += red[t + 32 * j];
    } else {
#pragma unroll
      for (int j = 0; j < 8; ++j) s += red[256 + (t - 32) + 32 * j];
    }
    atomicAdd(&colnorm[((size_t)n * NR + r) * KK + t], s);
  }
}

// ---------------------------------------------------------------------------
// K3: intra-norm + global-norm scaling, in place on d_out.
// After intra-norm each column k has squared-norm cn2/(cn2+eps), so the global
// squared-norm g is computable from the 64 column norms alone.
// ---------------------------------------------------------------------------
__global__ __launch_bounds__(256) void k3_scale(float* __restrict__ out,
                                                const float* __restrict__ colnorm) {
  int b = blockIdx.x;     // 1152 = 32*9*4
  int n = b / 36;
  int rem = b % 36;
  int r = rem / 4;
  int dc = rem % 4;

  __shared__ float ratio[64];
  __shared__ float fs[64];
  int t = threadIdx.x;
  float c = 0.f;
  if (t < 64) {
    c = colnorm[((size_t)n * NR + r) * KK + t];
    ratio[t] = c / (c + EPSF);
  }
  __syncthreads();
  if (t < 64) {
    float g = 0.f;
#pragma unroll
    for (int j = 0; j < 64; ++j) g += ratio[j];
    fs[t] = rsqrtf(c + EPSF) * rsqrtf(g + EPSF);
  }
  __syncthreads();

  size_t base4 = (((size_t)n * NR + r) * DD + (size_t)dc * 128) * KK / 4;
  float4* o4 = reinterpret_cast<float4*>(out);
  for (int j = 0; j < 8; ++j) {
    size_t idx = base4 + t + 256 * j;
    float4 v = o4[idx];
    int k0 = (int)((idx * 4) & 63);
    v.x *= fs[k0]; v.y *= fs[k0 + 1]; v.z *= fs[k0 + 2]; v.w *= fs[k0 + 3];
    o4[idx] = v;
  }
}

extern "C" void kernel_launch(void* const* d_in, const int* in_sizes, int n_in,
                              void* d_out, int out_size, void* d_ws, size_t ws_size,
                              hipStream_t stream) {
  const float* x  = (const float*)d_in[0];   // [32,36,36,512]
  const float* Wc = (const float*)d_in[1];   // [512,64]
  const float* C  = (const float*)d_in[2];   // [512,64]
  float* out = (float*)d_out;                // [32, 9*512*64]

  float* colnorm = (float*)d_ws;                       // 288*64 f32 = 73.7 KB
  float* a_ws    = (float*)d_ws + (size_t)NB * NR * KK; // 32*9*144*64 f32 = 10.6 MB

  hipMemsetAsync(colnorm, 0, (size_t)NB * NR * KK * sizeof(float), stream);
  k1_assign<<<NB * NR * 2, 256, 0, stream>>>(x, Wc, a_ws);
  k2_vlad<<<NB * NR * 4, 256, 0, stream>>>(x, C, a_ws, out, colnorm);
  k3_scale<<<NB * NR * 4, 256, 0, stream>>>(out, colnorm);
}

// Round 2
// 145.898 us; speedup vs baseline: 1.0442x; 1.0442x over previous
//
#include <hip/hip_runtime.h>

typedef __attribute__((ext_vector_type(4))) float f32x4;
typedef __attribute__((ext_vector_type(8))) short short8;

#define EPSF 1e-12f
#define SMEM_BYTES 148480

// LDS layout (byte offsets):
//   atH   0      64*192*2 = 24576   a^T hi  [k][p]  (p padded to 192, swizzled)
//   atL   24576  24576              a^T lo
//   asum  49152  256
//   cn2   49408  256
//   fs    49664  256                (pad to 50176)
//   pass1: xsH 50176 (18432) xsL 68608 (18432) wtH 87040 (8192) wtL 95232 (8192)
//   pass2: xtH 50176 (49152) xtL 99328 (49152)   -> total 148480

__device__ __forceinline__ ushort bf16rne(float x) {
  uint u = __float_as_uint(x);
  u += 0x7fffu + ((u >> 16) & 1u);
  return (ushort)(u >> 16);
}
__device__ __forceinline__ float bf2f(ushort h) {
  return __uint_as_float(((uint)h) << 16);
}
__device__ __forceinline__ f32x4 mfma16(short8 a, short8 b, f32x4 c) {
  return __builtin_amdgcn_mfma_f32_16x16x32_bf16(a, b, c, 0, 0, 0);
}
// swizzled b128 read: granule (8 bf16 = 16B) index XORed with row&7
__device__ __forceinline__ short8 ldsfrag(const ushort* base, int row, int kofs, int rowlen) {
  int g = kofs >> 3;
  int sg = g ^ (row & 7);
  return *(const short8*)(base + row * rowlen + (sg << 3));
}

extern "C" __global__ __launch_bounds__(512) void vlad_fused(
    const float* __restrict__ x, const float* __restrict__ Wc,
    const float* __restrict__ C, float* __restrict__ out) {
  extern __shared__ char smem[];
  ushort* atH = (ushort*)(smem);
  ushort* atL = (ushort*)(smem + 24576);
  float* asumS = (float*)(smem + 49152);
  float* cn2 = (float*)(smem + 49408);
  float* fsS = (float*)(smem + 49664);
  ushort* xsH = (ushort*)(smem + 50176);
  ushort* xsL = (ushort*)(smem + 68608);
  ushort* wtH = (ushort*)(smem + 87040);
  ushort* wtL = (ushort*)(smem + 95232);
  ushort* xtH = (ushort*)(smem + 50176);
  ushort* xtL = (ushort*)(smem + 99328);

  int b = blockIdx.x;
  int n = b / 9, r = b % 9;
  int y1 = (r / 3) * 12, x1 = (r % 3) * 12;
  int t = threadIdx.x;
  int w = t >> 6;
  int lane = t & 63;
  int l15 = lane & 15;
  int hi16 = lane >> 4;
  const float* xn = x + (size_t)n * (36 * 36 * 512);

  // ================= PASS 1: S = X * W  (M=144 pix, N=64 k, K=512 d) =========
  // wave w owns mi=w (16 rows); wave 0 also owns mi=8. 1mi x 4ni tiles.
  f32x4 accS[2][4];
#pragma unroll
  for (int i = 0; i < 2; ++i)
#pragma unroll
    for (int j = 0; j < 4; ++j) accS[i][j] = (f32x4){0.f, 0.f, 0.f, 0.f};

  for (int c = 0; c < 8; ++c) {  // d-chunks of 64
    int d0 = c * 64;
    // stage x tile [144 p][64 d] -> hi/lo bf16, granule-swizzled
    for (int task = t; task < 1152; task += 512) {
      int p = task >> 3, g = task & 7;
      int gy = y1 + p / 12, gx = x1 + p % 12;
      const float* src = xn + ((size_t)gy * 36 + gx) * 512 + d0 + g * 8;
      float4 v0 = *(const float4*)src;
      float4 v1 = *(const float4*)(src + 4);
      float vals[8] = {v0.x, v0.y, v0.z, v0.w, v1.x, v1.y, v1.z, v1.w};
      short8 h8, l8;
#pragma unroll
      for (int j = 0; j < 8; ++j) {
        ushort h = bf16rne(vals[j]);
        h8[j] = (short)h;
        l8[j] = (short)bf16rne(vals[j] - bf2f(h));
      }
      int sg = g ^ (p & 7);
      *(short8*)(xsH + p * 64 + sg * 8) = h8;
      *(short8*)(xsL + p * 64 + sg * 8) = l8;
    }
    // stage W chunk transposed: wt[k][d], hi/lo, swizzled (1 task/thread)
    {
      int d = t >> 3, kq = t & 7;
      const float* src = Wc + (size_t)(d0 + d) * 64 + kq * 8;
      float4 v0 = *(const float4*)src;
      float4 v1 = *(const float4*)(src + 4);
      float vals[8] = {v0.x, v0.y, v0.z, v0.w, v1.x, v1.y, v1.z, v1.w};
      int gd = d >> 3, off = d & 7;
#pragma unroll
      for (int j = 0; j < 8; ++j) {
        int k = kq * 8 + j;
        int sg = gd ^ (k & 7);
        ushort h = bf16rne(vals[j]);
        wtH[k * 64 + sg * 8 + off] = h;
        wtL[k * 64 + sg * 8 + off] = bf16rne(vals[j] - bf2f(h));
      }
    }
    __syncthreads();

#pragma unroll
    for (int ti = 0; ti < 2; ++ti) {
      int mi = ti ? 8 : w;
      if (ti == 0 || w == 0) {
        int arow = mi * 16 + l15;
#pragma unroll
        for (int ks = 0; ks < 2; ++ks) {
          int kofs = ks * 32 + hi16 * 8;
          short8 ah = ldsfrag(xsH, arow, kofs, 64);
          short8 al = ldsfrag(xsL, arow, kofs, 64);
#pragma unroll
          for (int ni = 0; ni < 4; ++ni) {
            short8 bh = ldsfrag(wtH, ni * 16 + l15, kofs, 64);
            short8 bl = ldsfrag(wtL, ni * 16 + l15, kofs, 64);
            f32x4 a0 = accS[ti][ni];
            a0 = mfma16(ah, bh, a0);
            a0 = mfma16(ah, bl, a0);
            a0 = mfma16(al, bh, a0);
            accS[ti][ni] = a0;
          }
        }
      }
    }
    __syncthreads();
  }

  // ============ softmax (in-register, per row) -> a^T bf16 hi/lo ============
#pragma unroll
  for (int ti = 0; ti < 2; ++ti) {
    int mi = ti ? 8 : w;
    if (ti == 0 || w == 0) {
#pragma unroll
      for (int rr = 0; rr < 4; ++rr) {
        float m = -1e30f;
#pragma unroll
        for (int ni = 0; ni < 4; ++ni) m = fmaxf(m, accS[ti][ni][rr]);
#pragma unroll
        for (int msk = 1; msk <= 8; msk <<= 1) m = fmaxf(m, __shfl_xor(m, msk));
        float e[4];
        float ssum = 0.f;
#pragma unroll
        for (int ni = 0; ni < 4; ++ni) {
          e[ni] = __expf(accS[ti][ni][rr] - m);
          ssum += e[ni];
        }
#pragma unroll
        for (int msk = 1; msk <= 8; msk <<= 1) ssum += __shfl_xor(ssum, msk);
        float inv = 1.f / ssum;
        int p = mi * 16 + hi16 * 4 + rr;
        int gp = p >> 3, offp = p & 7;
#pragma unroll
        for (int ni = 0; ni < 4; ++ni) {
          float a = e[ni] * inv;
          int k = ni * 16 + l15;
          int sg = gp ^ (k & 7);
          ushort h = bf16rne(a);
          atH[k * 192 + sg * 8 + offp] = h;
          atL[k * 192 + sg * 8 + offp] = bf16rne(a - bf2f(h));
        }
      }
    }
  }
  // zero-pad a^T for p in [144,160) (granules 18,19 of each row)
  for (int i = t; i < 128; i += 512) {
    int k = i >> 1, g = 18 + (i & 1);
    int sg = g ^ (k & 7);
    short8 z = {0, 0, 0, 0, 0, 0, 0, 0};
    *(short8*)(atH + k * 192 + sg * 8) = z;
    *(short8*)(atL + k * 192 + sg * 8) = z;
  }
  if (t < 64) cn2[t] = 0.f;
  __syncthreads();

  // asum[k] = sum_p a[p][k] (4 threads per k, 36 p each)
  if (t < 256) {
    int k = t >> 2, q = t & 3;
    float s = 0.f;
    for (int j = 0; j < 36; ++j) {
      int p = q * 36 + j;
      int sg = (p >> 3) ^ (k & 7);
      int idx = k * 192 + sg * 8 + (p & 7);
      s += bf2f(atH[idx]) + bf2f(atL[idx]);
    }
    s += __shfl_xor(s, 1);
    s += __shfl_xor(s, 2);
    if (q == 0) asumS[k] = s;
  }
  __syncthreads();

  // ========= PASS 2: V = X^T * A - C*asum  (M=512 d, N=64 k, K=144 p) =======
  // d-chunks of 128: 8mi x 4ni frags -> wave tile 2mi x 2ni (perfect 8-way).
  int miB = (w >> 1) << 1;
  int kbase = (w & 1) * 32;
  int k0 = kbase + l15, k1 = kbase + 16 + l15;
  f32x4 vk[16];
  float cnp0 = 0.f, cnp1 = 0.f;

#pragma unroll
  for (int c = 0; c < 4; ++c) {
    int d0 = c * 128;
    // stage x^T [128 d][192 p] hi/lo (transpose during staging)
    for (int task = t; task < 2304; task += 512) {
      int p = task >> 4, dg = task & 15;
      int gy = y1 + p / 12, gx = x1 + p % 12;
      const float* src = xn + ((size_t)gy * 36 + gx) * 512 + d0 + dg * 8;
      float4 v0 = *(const float4*)src;
      float4 v1 = *(const float4*)(src + 4);
      float vals[8] = {v0.x, v0.y, v0.z, v0.w, v1.x, v1.y, v1.z, v1.w};
      int gp = p >> 3, offp = p & 7;
#pragma unroll
      for (int j = 0; j < 8; ++j) {
        int d = dg * 8 + j;
        int sg = gp ^ (d & 7);
        ushort h = bf16rne(vals[j]);
        xtH[d * 192 + sg * 8 + offp] = h;
        xtL[d * 192 + sg * 8 + offp] = bf16rne(vals[j] - bf2f(h));
      }
    }
    for (int i = t; i < 256; i += 512) {
      int d = i >> 1, g = 18 + (i & 1);
      int sg = g ^ (d & 7);
      short8 z = {0, 0, 0, 0, 0, 0, 0, 0};
      *(short8*)(xtH + d * 192 + sg * 8) = z;
      *(short8*)(xtL + d * 192 + sg * 8) = z;
    }
    __syncthreads();

    f32x4 acc[2][2];
#pragma unroll
    for (int i = 0; i < 2; ++i)
#pragma unroll
      for (int j = 0; j < 2; ++j) acc[i][j] = (f32x4){0.f, 0.f, 0.f, 0.f};

#pragma unroll
    for (int ks = 0; ks < 5; ++ks) {
      int kofs = ks * 32 + hi16 * 8;
      short8 ah0 = ldsfrag(xtH, (miB + 0) * 16 + l15, kofs, 192);
      short8 al0 = ldsfrag(xtL, (miB + 0) * 16 + l15, kofs, 192);
      short8 ah1 = ldsfrag(xtH, (miB + 1) * 16 + l15, kofs, 192);
      short8 al1 = ldsfrag(xtL, (miB + 1) * 16 + l15, kofs, 192);
      short8 bh0 = ldsfrag(atH, kbase + l15, kofs, 192);
      short8 bl0 = ldsfrag(atL, kbase + l15, kofs, 192);
      short8 bh1 = ldsfrag(atH, kbase + 16 + l15, kofs, 192);
      short8 bl1 = ldsfrag(atL, kbase + 16 + l15, kofs, 192);
      acc[0][0] = mfma16(ah0, bh0, acc[0][0]);
      acc[0][0] = mfma16(ah0, bl0, acc[0][0]);
      acc[0][0] = mfma16(al0, bh0, acc[0][0]);
      acc[0][1] = mfma16(ah0, bh1, acc[0][1]);
      acc[0][1] = mfma16(ah0, bl1, acc[0][1]);
      acc[0][1] = mfma16(al0, bh1, acc[0][1]);
      acc[1][0] = mfma16(ah1, bh0, acc[1][0]);
      acc[1][0] = mfma16(ah1, bl0, acc[1][0]);
      acc[1][0] = mfma16(al1, bh0, acc[1][0]);
      acc[1][1] = mfma16(ah1, bh1, acc[1][1]);
      acc[1][1] = mfma16(ah1, bl1, acc[1][1]);
      acc[1][1] = mfma16(al1, bh1, acc[1][1]);
    }
    __syncthreads();

    // postproc: v = acc - C*asum; accumulate colnorm^2; keep v in regs
#pragma unroll
    for (int m01 = 0; m01 < 2; ++m01) {
#pragma unroll
      for (int n01 = 0; n01 < 2; ++n01) {
        int k = kbase + n01 * 16 + l15;
        float ak = asumS[k];
#pragma unroll
        for (int rr = 0; rr < 4; ++rr) {
          int dd = d0 + (miB + m01) * 16 + hi16 * 4 + rr;
          float v = acc[m01][n01][rr] - C[(size_t)dd * 64 + k] * ak;
          vk[(c * 2 + m01) * 2 + n01][rr] = v;
          if (n01 == 0) cnp0 += v * v; else cnp1 += v * v;
        }
      }
    }
  }

  atomicAdd(&cn2[k0], cnp0);
  atomicAdd(&cn2[k1], cnp1);
  __syncthreads();
  if (t < 64) {
    float cc = cn2[t];
    float g_ = 0.f;
#pragma unroll
    for (int j = 0; j < 64; ++j) {
      float cj = cn2[j];
      g_ += cj / (cj + EPSF);
    }
    fsS[t] = rsqrtf(cc + EPSF) * rsqrtf(g_ + EPSF);
  }
  __syncthreads();

  size_t obase = ((size_t)n * 9 + r) * (512 * 64);
  float f0 = fsS[k0], f1 = fsS[k1];
#pragma unroll
  for (int c = 0; c < 4; ++c)
#pragma unroll
    for (int m01 = 0; m01 < 2; ++m01)
#pragma unroll
      for (int n01 = 0; n01 < 2; ++n01) {
        int k = n01 ? k1 : k0;
        float ff = n01 ? f1 : f0;
#pragma unroll
        for (int rr = 0; rr < 4; ++rr) {
          int dd = c * 128 + (miB + m01) * 16 + hi16 * 4 + rr;
          out[obase + (size_t)dd * 64 + k] = vk[(c * 2 + m01) * 2 + n01][rr] * ff;
        }
      }
}

extern "C" void kernel_launch(void* const* d_in, const int* in_sizes, int n_in,
                              void* d_out, int out_size, void* d_ws, size_t ws_size,
                              hipStream_t stream) {
  const float* x = (const float*)d_in[0];   // [32,36,36,512]
  const float* Wc = (const float*)d_in[1];  // [512,64]
  const float* C = (const float*)d_in[2];   // [512,64]
  float* out = (float*)d_out;               // [32, 9*512*64]

  hipFuncSetAttribute((const void*)vlad_fused,
                      hipFuncAttributeMaxDynamicSharedMemorySize, SMEM_BYTES);
  vlad_fused<<<288, 512, SMEM_BYTES, stream>>>(x, Wc, C, out);
}

// Round 3
// 106.419 us; speedup vs baseline: 1.4315x; 1.3710x over previous
//
#include <hip/hip_runtime.h>

typedef __attribute__((ext_vector_type(4))) float f32x4;
typedef __attribute__((ext_vector_type(8))) short short8;

#define EPSF 1e-12f

__device__ __forceinline__ ushort bf16rne(float x) {
  uint u = __float_as_uint(x);
  u += 0x7fffu + ((u >> 16) & 1u);
  return (ushort)(u >> 16);
}
__device__ __forceinline__ float bf2f(ushort h) {
  return __uint_as_float(((uint)h) << 16);
}
__device__ __forceinline__ f32x4 mfma16(short8 a, short8 b, f32x4 c) {
  return __builtin_amdgcn_mfma_f32_16x16x32_bf16(a, b, c, 0, 0, 0);
}
// rowlen 64 ushorts (8 granules of 8): XOR-swizzle granule with row&7
__device__ __forceinline__ short8 frag64(const ushort* base, int row, int kofs) {
  int g = kofs >> 3;
  int sg = g ^ (row & 7);
  return *(const short8*)(base + row * 64 + (sg << 3));
}
// rowlen 144 ushorts (18 granules): swizzle only granules 0..15
__device__ __forceinline__ short8 frag144(const ushort* base, int row, int kofs) {
  int g = kofs >> 3;
  int sg = (g < 16) ? (g ^ (row & 7)) : g;
  return *(const short8*)(base + row * 144 + (sg << 3));
}

// ---------------------------------------------------------------------------
// K0: W [512][64] f32 -> W^T bf16 hi/lo in ws: [2][64 k][512 d]
// ---------------------------------------------------------------------------
__global__ __launch_bounds__(256) void k0_wt(const float* __restrict__ W,
                                             ushort* __restrict__ wsWT) {
  int k = blockIdx.x;  // 64
  for (int d = threadIdx.x; d < 512; d += 256) {
    float v = W[(size_t)d * 64 + k];
    ushort h = bf16rne(v);
    wsWT[k * 512 + d] = h;
    wsWT[32768 + k * 512 + d] = bf16rne(v - bf2f(h));
  }
}

// ---------------------------------------------------------------------------
// K1: per (n,r): s^T = W^T * x  (A=W^T [k][d], B=x [p][d] natural!), softmax
// over k, write a^T [k][p] bf16 hi/lo (swizzled, K2-ready) + asum to ws.
// 512 thr = 8 waves; wave w owns p-cols [16w,16w+16); wave 0 also [128,144).
// Reg-prefetch double-buffer on the global->LDS staging.
// ---------------------------------------------------------------------------
__global__ __launch_bounds__(512) void k1_assign(const float* __restrict__ x,
                                                 const ushort* __restrict__ wsWT,
                                                 ushort* __restrict__ aT_ws,
                                                 float* __restrict__ asum_ws) {
  __shared__ char sm[53504];
  ushort* xsH = (ushort*)(sm);            // [144 p][64 d] 18432 B
  ushort* xsL = (ushort*)(sm + 18432);
  ushort* wtH = (ushort*)(sm + 36864);    // [64 k][64 d] 8192 B
  ushort* wtL = (ushort*)(sm + 45056);
  ushort* atH = (ushort*)(sm);            // overlay after MFMA: [64 k][144 p]
  ushort* atL = (ushort*)(sm + 18432);
  float* asumS = (float*)(sm + 53248);

  int b = blockIdx.x;
  int n = b / 9, r = b % 9;
  int y1 = (r / 3) * 12, x1 = (r % 3) * 12;
  int t = threadIdx.x;
  int w = t >> 6;
  int lane = t & 63, l15 = lane & 15, hi16 = lane >> 4;
  const float* xn = x + (size_t)n * (36 * 36 * 512);
  if (t < 64) asumS[t] = 0.f;

  float4 px[3][2];
  short8 pwH, pwL;
  int ntask = (t < 128) ? 3 : 2;
  int wk = t >> 3, wg = t & 7;   // W^T staging task

  f32x4 acc[4][2];
#pragma unroll
  for (int mi = 0; mi < 4; ++mi) {
    acc[mi][0] = (f32x4){0.f, 0.f, 0.f, 0.f};
    acc[mi][1] = (f32x4){0.f, 0.f, 0.f, 0.f};
  }

  // -------- prefetch chunk 0 --------
  {
    int d0 = 0;
#pragma unroll
    for (int i = 0; i < 3; ++i)
      if (i < ntask) {
        int task = t + i * 512;
        int p = task >> 3, g = task & 7;
        const float* src = xn + ((size_t)(y1 + p / 12) * 36 + (x1 + p % 12)) * 512 + d0 + g * 8;
        px[i][0] = *(const float4*)src;
        px[i][1] = *(const float4*)(src + 4);
      }
    pwH = *(const short8*)(wsWT + wk * 512 + d0 + wg * 8);
    pwL = *(const short8*)(wsWT + 32768 + wk * 512 + d0 + wg * 8);
  }

  for (int c = 0; c < 8; ++c) {
    __syncthreads();  // previous MFMA reads done -> LDS writable
    // commit prefetched chunk c
#pragma unroll
    for (int i = 0; i < 3; ++i)
      if (i < ntask) {
        int task = t + i * 512;
        int p = task >> 3, g = task & 7;
        float vals[8] = {px[i][0].x, px[i][0].y, px[i][0].z, px[i][0].w,
                         px[i][1].x, px[i][1].y, px[i][1].z, px[i][1].w};
        short8 h8, l8;
#pragma unroll
        for (int j = 0; j < 8; ++j) {
          ushort h = bf16rne(vals[j]);
          h8[j] = (short)h;
          l8[j] = (short)bf16rne(vals[j] - bf2f(h));
        }
        int sg = g ^ (p & 7);
        *(short8*)(xsH + p * 64 + (sg << 3)) = h8;
        *(short8*)(xsL + p * 64 + (sg << 3)) = l8;
      }
    {
      int sg = wg ^ (wk & 7);
      *(short8*)(wtH + wk * 64 + (sg << 3)) = pwH;
      *(short8*)(wtL + wk * 64 + (sg << 3)) = pwL;
    }
    // issue prefetch for chunk c+1 (overlaps with MFMA below)
    if (c < 7) {
      int d0 = (c + 1) * 64;
#pragma unroll
      for (int i = 0; i < 3; ++i)
        if (i < ntask) {
          int task = t + i * 512;
          int p = task >> 3, g = task & 7;
          const float* src = xn + ((size_t)(y1 + p / 12) * 36 + (x1 + p % 12)) * 512 + d0 + g * 8;
          px[i][0] = *(const float4*)src;
          px[i][1] = *(const float4*)(src + 4);
        }
      pwH = *(const short8*)(wsWT + wk * 512 + d0 + wg * 8);
      pwL = *(const short8*)(wsWT + 32768 + wk * 512 + d0 + wg * 8);
    }
    __syncthreads();

#pragma unroll
    for (int ks = 0; ks < 2; ++ks) {
      int kofs = ks * 32 + hi16 * 8;
      short8 aH[4], aL[4];
#pragma unroll
      for (int mi = 0; mi < 4; ++mi) {
        aH[mi] = frag64(wtH, mi * 16 + l15, kofs);
        aL[mi] = frag64(wtL, mi * 16 + l15, kofs);
      }
      {
        short8 bH = frag64(xsH, w * 16 + l15, kofs);
        short8 bL = frag64(xsL, w * 16 + l15, kofs);
#pragma unroll
        for (int mi = 0; mi < 4; ++mi) {
          f32x4 a0 = acc[mi][0];
          a0 = mfma16(aH[mi], bH, a0);
          a0 = mfma16(aH[mi], bL, a0);
          a0 = mfma16(aL[mi], bH, a0);
          acc[mi][0] = a0;
        }
      }
      if (w == 0) {
        short8 bH = frag64(xsH, 128 + l15, kofs);
        short8 bL = frag64(xsL, 128 + l15, kofs);
#pragma unroll
        for (int mi = 0; mi < 4; ++mi) {
          f32x4 a0 = acc[mi][1];
          a0 = mfma16(aH[mi], bH, a0);
          a0 = mfma16(aH[mi], bL, a0);
          a0 = mfma16(aL[mi], bH, a0);
          acc[mi][1] = a0;
        }
      }
    }
  }
  __syncthreads();  // all MFMA LDS reads done -> overlay a^T

  float part[4][4];
#pragma unroll
  for (int mi = 0; mi < 4; ++mi)
#pragma unroll
    for (int rr = 0; rr < 4; ++rr) part[mi][rr] = 0.f;

  // ---- softmax ti=0 (p = w*16 + l15) ----
  {
    int p = w * 16 + l15;
    float m = -1e30f;
#pragma unroll
    for (int mi = 0; mi < 4; ++mi)
#pragma unroll
      for (int rr = 0; rr < 4; ++rr) m = fmaxf(m, acc[mi][0][rr]);
    m = fmaxf(m, __shfl_xor(m, 16));
    m = fmaxf(m, __shfl_xor(m, 32));
    float e[4][4], sum = 0.f;
#pragma unroll
    for (int mi = 0; mi < 4; ++mi)
#pragma unroll
      for (int rr = 0; rr < 4; ++rr) {
        e[mi][rr] = __expf(acc[mi][0][rr] - m);
        sum += e[mi][rr];
      }
    sum += __shfl_xor(sum, 16);
    sum += __shfl_xor(sum, 32);
    float inv = 1.f / sum;
    int gp = p >> 3, pl = p & 7;
#pragma unroll
    for (int mi = 0; mi < 4; ++mi)
#pragma unroll
      for (int rr = 0; rr < 4; ++rr) {
        float a = e[mi][rr] * inv;
        part[mi][rr] += a;
        int k = mi * 16 + hi16 * 4 + rr;
        int sg = gp ^ (k & 7);  // gp <= 15 here
        int idx = k * 144 + (sg << 3) + pl;
        ushort h = bf16rne(a);
        atH[idx] = h;
        atL[idx] = bf16rne(a - bf2f(h));
      }
  }
  // ---- softmax ti=1 (wave 0 only, p = 128 + l15) ----
  if (w == 0) {
    int p = 128 + l15;
    float m = -1e30f;
#pragma unroll
    for (int mi = 0; mi < 4; ++mi)
#pragma unroll
      for (int rr = 0; rr < 4; ++rr) m = fmaxf(m, acc[mi][1][rr]);
    m = fmaxf(m, __shfl_xor(m, 16));
    m = fmaxf(m, __shfl_xor(m, 32));
    float e[4][4], sum = 0.f;
#pragma unroll
    for (int mi = 0; mi < 4; ++mi)
#pragma unroll
      for (int rr = 0; rr < 4; ++rr) {
        e[mi][rr] = __expf(acc[mi][1][rr] - m);
        sum += e[mi][rr];
      }
    sum += __shfl_xor(sum, 16);
    sum += __shfl_xor(sum, 32);
    float inv = 1.f / sum;
    int gp = p >> 3, pl = p & 7;  // gp in {16,17}: unswizzled
#pragma unroll
    for (int mi = 0; mi < 4; ++mi)
#pragma unroll
      for (int rr = 0; rr < 4; ++rr) {
        float a = e[mi][rr] * inv;
        part[mi][rr] += a;
        int k = mi * 16 + hi16 * 4 + rr;
        int idx = k * 144 + (gp << 3) + pl;
        ushort h = bf16rne(a);
        atH[idx] = h;
        atL[idx] = bf16rne(a - bf2f(h));
      }
  }
  // asum: reduce over l15 then one atomic per k
#pragma unroll
  for (int mi = 0; mi < 4; ++mi)
#pragma unroll
    for (int rr = 0; rr < 4; ++rr) {
      float s = part[mi][rr];
      s += __shfl_xor(s, 1);
      s += __shfl_xor(s, 2);
      s += __shfl_xor(s, 4);
      s += __shfl_xor(s, 8);
      if (l15 == 0) atomicAdd(&asumS[mi * 16 + hi16 * 4 + rr], s);
    }
  __syncthreads();

  // dump a^T (36864 B contiguous at sm) + asum to ws
  {
    float4* dst = (float4*)(aT_ws + (size_t)b * 18432);
    const float4* src = (const float4*)sm;
    for (int i = t; i < 2304; i += 512) dst[i] = src[i];
    if (t < 64) asum_ws[b * 64 + t] = asumS[t];
  }
}

// ---------------------------------------------------------------------------
// K2: per (n,r,dc of 64): V = X^T * A - C*asum. A-frag = x^T (local transpose
// with rotation+swizzle), B-frag = a^T straight from ws. Raw v -> out,
// colnorm^2 -> ws atomics.
// ---------------------------------------------------------------------------
extern "C" __global__ __launch_bounds__(256) void k2_vlad(
    const float* __restrict__ x, const float* __restrict__ C,
    const ushort* __restrict__ aT_ws, const float* __restrict__ asum_ws,
    float* __restrict__ out, float* __restrict__ colnorm) {
  extern __shared__ char sm[];
  ushort* xtH = (ushort*)(sm);            // [64 d][144 p] 18432 B
  ushort* xtL = (ushort*)(sm + 18432);
  ushort* atH = (ushort*)(sm + 36864);    // [64 k][144 p]
  ushort* atL = (ushort*)(sm + 55296);
  float* asumS = (float*)(sm + 73728);
  float* cn2 = (float*)(sm + 73984);

  int b = blockIdx.x;  // 2304 = 288*8
  int reg = b >> 3, dc = b & 7;
  int n = reg / 9, r = reg % 9;
  int d0 = dc * 64;
  int y1 = (r / 3) * 12, x1 = (r % 3) * 12;
  int t = threadIdx.x;
  int w = t >> 6, lane = t & 63, l15 = lane & 15, hi16 = lane >> 4;
  const float* xn = x + (size_t)n * (36 * 36 * 512);

  if (t < 64) {
    asumS[t] = asum_ws[reg * 64 + t];
    cn2[t] = 0.f;
  }
  // stage a^T (already swizzled in ws)
  {
    const float4* src = (const float4*)(aT_ws + (size_t)reg * 18432);
    float4* dst = (float4*)(sm + 36864);
    for (int i = t; i < 2304; i += 256) dst[i] = src[i];
  }
  // stage x^T: transpose-scatter with lane rotation for bank spread
  for (int task = t; task < 1152; task += 256) {
    int p = task >> 3, dg = task & 7;
    const float* src = xn + ((size_t)(y1 + p / 12) * 36 + (x1 + p % 12)) * 512 + d0 + dg * 8;
    float4 v0 = *(const float4*)src;
    float4 v1 = *(const float4*)(src + 4);
    float vals[8] = {v0.x, v0.y, v0.z, v0.w, v1.x, v1.y, v1.z, v1.w};
    int gp = p >> 3, pl = p & 7;
#pragma unroll
    for (int j = 0; j < 8; ++j) {
      int e = (j + dg) & 7;
      int d = dg * 8 + e;
      float v = vals[e];
      ushort h = bf16rne(v);
      int sg = (gp < 16) ? (gp ^ (d & 7)) : gp;
      int idx = d * 144 + (sg << 3) + pl;
      xtH[idx] = h;
      xtL[idx] = bf16rne(v - bf2f(h));
    }
  }
  __syncthreads();

  f32x4 acc[4];
#pragma unroll
  for (int ni = 0; ni < 4; ++ni) acc[ni] = (f32x4){0.f, 0.f, 0.f, 0.f};
  int arow = w * 16 + l15;
  short8 z8 = {0, 0, 0, 0, 0, 0, 0, 0};

#pragma unroll
  for (int ks = 0; ks < 5; ++ks) {
    bool tail = (ks == 4) && (hi16 >= 2);
    int kofs = tail ? (hi16 * 8) : (ks * 32 + hi16 * 8);  // keep addr in-range
    short8 aH = tail ? z8 : frag144(xtH, arow, kofs);
    short8 aL = tail ? z8 : frag144(xtL, arow, kofs);
#pragma unroll
    for (int ni = 0; ni < 4; ++ni) {
      short8 bH = tail ? z8 : frag144(atH, ni * 16 + l15, kofs);
      short8 bL = tail ? z8 : frag144(atL, ni * 16 + l15, kofs);
      f32x4 a0 = acc[ni];
      a0 = mfma16(aH, bH, a0);
      a0 = mfma16(aH, bL, a0);
      a0 = mfma16(aL, bH, a0);
      acc[ni] = a0;
    }
  }

  size_t obase = (size_t)reg * (512 * 64);
#pragma unroll
  for (int ni = 0; ni < 4; ++ni) {
    int k = ni * 16 + l15;
    float ak = asumS[k];
    float s2 = 0.f;
#pragma unroll
    for (int rr = 0; rr < 4; ++rr) {
      int d = d0 + w * 16 + hi16 * 4 + rr;
      float v = acc[ni][rr] - C[(size_t)d * 64 + k] * ak;
      out[obase + (size_t)d * 64 + k] = v;
      s2 += v * v;
    }
    atomicAdd(&cn2[k], s2);
  }
  __syncthreads();
  if (t < 64) atomicAdd(&colnorm[reg * 64 + t], cn2[t]);
}

// ---------------------------------------------------------------------------
// K3: intra-norm + global-norm scaling in place (validated in R0).
// ---------------------------------------------------------------------------
__global__ __launch_bounds__(256) void k3_scale(float* __restrict__ out,
                                                const float* __restrict__ colnorm) {
  int b = blockIdx.x;  // 1152 = 288*4
  int reg = b >> 2, dc = b & 3;

  __shared__ float ratio[64];
  __shared__ float fs[64];
  int t = threadIdx.x;
  float c = 0.f;
  if (t < 64) {
    c = colnorm[reg * 64 + t];
    ratio[t] = c / (c + EPSF);
  }
  __syncthreads();
  if (t < 64) {
    float g = 0.f;
#pragma unroll
    for (int j = 0; j < 64; ++j) g += ratio[j];
    fs[t] = rsqrtf(c + EPSF) * rsqrtf(g + EPSF);
  }
  __syncthreads();

  size_t base4 = (((size_t)reg * 512) + (size_t)dc * 128) * 64 / 4;
  float4* o4 = reinterpret_cast<float4*>(out);
  for (int j = 0; j < 8; ++j) {
    size_t idx = base4 + t + 256 * j;
    float4 v = o4[idx];
    int k0 = (int)((idx * 4) & 63);
    v.x *= fs[k0]; v.y *= fs[k0 + 1]; v.z *= fs[k0 + 2]; v.w *= fs[k0 + 3];
    o4[idx] = v;
  }
}

extern "C" void kernel_launch(void* const* d_in, const int* in_sizes, int n_in,
                              void* d_out, int out_size, void* d_ws, size_t ws_size,
                              hipStream_t stream) {
  const float* x = (const float*)d_in[0];   // [32,36,36,512]
  const float* Wc = (const float*)d_in[1];  // [512,64]
  const float* C = (const float*)d_in[2];   // [512,64]
  float* out = (float*)d_out;

  char* ws = (char*)d_ws;
  ushort* wsWT = (ushort*)(ws);                 // 131072 B
  float* asum_ws = (float*)(ws + 131072);       // 73728 B
  float* colnorm = (float*)(ws + 204800);       // 73728 B
  ushort* aT_ws = (ushort*)(ws + 278528);       // 10,616,832 B

  hipMemsetAsync(colnorm, 0, 288 * 64 * sizeof(float), stream);
  k0_wt<<<64, 256, 0, stream>>>(Wc, wsWT);
  k1_assign<<<288, 512, 0, stream>>>(x, wsWT, aT_ws, asum_ws);
  hipFuncSetAttribute((const void*)k2_vlad,
                      hipFuncAttributeMaxDynamicSharedMemorySize, 74240);
  k2_vlad<<<2304, 256, 74240, stream>>>(x, C, aT_ws, asum_ws, out, colnorm);
  k3_scale<<<1152, 256, 0, stream>>>(out, colnorm);
}

// Round 4
// 86.320 us; speedup vs baseline: 1.7648x; 1.2328x over previous
//
#include <hip/hip_runtime.h>

typedef __attribute__((ext_vector_type(4))) float f32x4;
typedef __attribute__((ext_vector_type(8))) short short8;

#define EPSF 1e-12f

__device__ __forceinline__ ushort bf16rne(float x) {
  uint u = __float_as_uint(x);
  u += 0x7fffu + ((u >> 16) & 1u);
  return (ushort)(u >> 16);
}
__device__ __forceinline__ float bf2f(ushort h) {
  return __uint_as_float(((uint)h) << 16);
}
__device__ __forceinline__ f32x4 mfma16(short8 a, short8 b, f32x4 c) {
  return __builtin_amdgcn_mfma_f32_16x16x32_bf16(a, b, c, 0, 0, 0);
}
// rowlen 64 ushorts (8 granules of 8): XOR-swizzle granule with row&7
__device__ __forceinline__ short8 frag64(const ushort* base, int row, int kofs) {
  int g = kofs >> 3;
  int sg = g ^ (row & 7);
  return *(const short8*)(base + row * 64 + (sg << 3));
}

// ---------------------------------------------------------------------------
// K0: W [512][64] f32 -> W^T bf16 hi/lo in ws: [2][64 k][512 d]
// ---------------------------------------------------------------------------
__global__ __launch_bounds__(256) void k0_wt(const float* __restrict__ W,
                                             ushort* __restrict__ wsWT) {
  int k = blockIdx.x;  // 64
  for (int d = threadIdx.x; d < 512; d += 256) {
    float v = W[(size_t)d * 64 + k];
    ushort h = bf16rne(v);
    wsWT[k * 512 + d] = h;
    wsWT[32768 + k * 512 + d] = bf16rne(v - bf2f(h));
  }
}

// ---------------------------------------------------------------------------
// K1: per (n,r): s^T = W^T * x (A=W^T [k][d], B=x [p][d] natural), softmax
// over k, dump a^T [2 planes][64 k][19 float4 = 152-pad p] UNswizzled to ws
// (k2-ready linear copy) + asum. Reg-prefetch double-buffered staging.
// ---------------------------------------------------------------------------
__global__ __launch_bounds__(512) void k1_assign(const float* __restrict__ x,
                                                 const ushort* __restrict__ wsWT,
                                                 float4* __restrict__ aT_ws,
                                                 float* __restrict__ asum_ws) {
  __shared__ char sm[53504];
  ushort* xsH = (ushort*)(sm);            // [144 p][64 d] 18432 B
  ushort* xsL = (ushort*)(sm + 18432);
  ushort* wtH = (ushort*)(sm + 36864);    // [64 k][64 d] 8192 B
  ushort* wtL = (ushort*)(sm + 45056);
  // overlay after MFMA: a^T [64 k][144 p] swizzled granules, hi at 0, lo at 18432
  ushort* atH = (ushort*)(sm);
  ushort* atL = (ushort*)(sm + 18432);
  float* asumS = (float*)(sm + 53248);

  int b = blockIdx.x;
  int n = b / 9, r = b % 9;
  int y1 = (r / 3) * 12, x1 = (r % 3) * 12;
  int t = threadIdx.x;
  int w = t >> 6;
  int lane = t & 63, l15 = lane & 15, hi16 = lane >> 4;
  const float* xn = x + (size_t)n * (36 * 36 * 512);
  if (t < 64) asumS[t] = 0.f;

  float4 px[3][2];
  short8 pwH, pwL;
  int ntask = (t < 128) ? 3 : 2;
  int wk = t >> 3, wg = t & 7;   // W^T staging task

  f32x4 acc[4][2];
#pragma unroll
  for (int mi = 0; mi < 4; ++mi) {
    acc[mi][0] = (f32x4){0.f, 0.f, 0.f, 0.f};
    acc[mi][1] = (f32x4){0.f, 0.f, 0.f, 0.f};
  }

  // -------- prefetch chunk 0 --------
  {
    int d0 = 0;
#pragma unroll
    for (int i = 0; i < 3; ++i)
      if (i < ntask) {
        int task = t + i * 512;
        int p = task >> 3, g = task & 7;
        const float* src = xn + ((size_t)(y1 + p / 12) * 36 + (x1 + p % 12)) * 512 + d0 + g * 8;
        px[i][0] = *(const float4*)src;
        px[i][1] = *(const float4*)(src + 4);
      }
    pwH = *(const short8*)(wsWT + wk * 512 + d0 + wg * 8);
    pwL = *(const short8*)(wsWT + 32768 + wk * 512 + d0 + wg * 8);
  }

  for (int c = 0; c < 8; ++c) {
    __syncthreads();
#pragma unroll
    for (int i = 0; i < 3; ++i)
      if (i < ntask) {
        int task = t + i * 512;
        int p = task >> 3, g = task & 7;
        float vals[8] = {px[i][0].x, px[i][0].y, px[i][0].z, px[i][0].w,
                         px[i][1].x, px[i][1].y, px[i][1].z, px[i][1].w};
        short8 h8, l8;
#pragma unroll
        for (int j = 0; j < 8; ++j) {
          ushort h = bf16rne(vals[j]);
          h8[j] = (short)h;
          l8[j] = (short)bf16rne(vals[j] - bf2f(h));
        }
        int sg = g ^ (p & 7);
        *(short8*)(xsH + p * 64 + (sg << 3)) = h8;
        *(short8*)(xsL + p * 64 + (sg << 3)) = l8;
      }
    {
      int sg = wg ^ (wk & 7);
      *(short8*)(wtH + wk * 64 + (sg << 3)) = pwH;
      *(short8*)(wtL + wk * 64 + (sg << 3)) = pwL;
    }
    if (c < 7) {
      int d0 = (c + 1) * 64;
#pragma unroll
      for (int i = 0; i < 3; ++i)
        if (i < ntask) {
          int task = t + i * 512;
          int p = task >> 3, g = task & 7;
          const float* src = xn + ((size_t)(y1 + p / 12) * 36 + (x1 + p % 12)) * 512 + d0 + g * 8;
          px[i][0] = *(const float4*)src;
          px[i][1] = *(const float4*)(src + 4);
        }
      pwH = *(const short8*)(wsWT + wk * 512 + d0 + wg * 8);
      pwL = *(const short8*)(wsWT + 32768 + wk * 512 + d0 + wg * 8);
    }
    __syncthreads();

#pragma unroll
    for (int ks = 0; ks < 2; ++ks) {
      int kofs = ks * 32 + hi16 * 8;
      short8 aH[4], aL[4];
#pragma unroll
      for (int mi = 0; mi < 4; ++mi) {
        aH[mi] = frag64(wtH, mi * 16 + l15, kofs);
        aL[mi] = frag64(wtL, mi * 16 + l15, kofs);
      }
      {
        short8 bH = frag64(xsH, w * 16 + l15, kofs);
        short8 bL = frag64(xsL, w * 16 + l15, kofs);
#pragma unroll
        for (int mi = 0; mi < 4; ++mi) {
          f32x4 a0 = acc[mi][0];
          a0 = mfma16(aH[mi], bH, a0);
          a0 = mfma16(aH[mi], bL, a0);
          a0 = mfma16(aL[mi], bH, a0);
          acc[mi][0] = a0;
        }
      }
      if (w == 0) {
        short8 bH = frag64(xsH, 128 + l15, kofs);
        short8 bL = frag64(xsL, 128 + l15, kofs);
#pragma unroll
        for (int mi = 0; mi < 4; ++mi) {
          f32x4 a0 = acc[mi][1];
          a0 = mfma16(aH[mi], bH, a0);
          a0 = mfma16(aH[mi], bL, a0);
          a0 = mfma16(aL[mi], bH, a0);
          acc[mi][1] = a0;
        }
      }
    }
  }
  __syncthreads();  // all MFMA LDS reads done -> overlay a^T

  float part[4][4];
#pragma unroll
  for (int mi = 0; mi < 4; ++mi)
#pragma unroll
    for (int rr = 0; rr < 4; ++rr) part[mi][rr] = 0.f;

  // ---- softmax ti=0 (p = w*16 + l15) ----
  {
    int p = w * 16 + l15;
    float m = -1e30f;
#pragma unroll
    for (int mi = 0; mi < 4; ++mi)
#pragma unroll
      for (int rr = 0; rr < 4; ++rr) m = fmaxf(m, acc[mi][0][rr]);
    m = fmaxf(m, __shfl_xor(m, 16));
    m = fmaxf(m, __shfl_xor(m, 32));
    float e[4][4], sum = 0.f;
#pragma unroll
    for (int mi = 0; mi < 4; ++mi)
#pragma unroll
      for (int rr = 0; rr < 4; ++rr) {
        e[mi][rr] = __expf(acc[mi][0][rr] - m);
        sum += e[mi][rr];
      }
    sum += __shfl_xor(sum, 16);
    sum += __shfl_xor(sum, 32);
    float inv = 1.f / sum;
    int gp = p >> 3, pl = p & 7;
#pragma unroll
    for (int mi = 0; mi < 4; ++mi)
#pragma unroll
      for (int rr = 0; rr < 4; ++rr) {
        float a = e[mi][rr] * inv;
        part[mi][rr] += a;
        int k = mi * 16 + hi16 * 4 + rr;
        int sg = gp ^ (k & 7);
        int idx = k * 144 + (sg << 3) + pl;
        ushort h = bf16rne(a);
        atH[idx] = h;
        atL[idx] = bf16rne(a - bf2f(h));
      }
  }
  // ---- softmax ti=1 (wave 0 only, p = 128 + l15) ----
  if (w == 0) {
    int p = 128 + l15;
    float m = -1e30f;
#pragma unroll
    for (int mi = 0; mi < 4; ++mi)
#pragma unroll
      for (int rr = 0; rr < 4; ++rr) m = fmaxf(m, acc[mi][1][rr]);
    m = fmaxf(m, __shfl_xor(m, 16));
    m = fmaxf(m, __shfl_xor(m, 32));
    float e[4][4], sum = 0.f;
#pragma unroll
    for (int mi = 0; mi < 4; ++mi)
#pragma unroll
      for (int rr = 0; rr < 4; ++rr) {
        e[mi][rr] = __expf(acc[mi][1][rr] - m);
        sum += e[mi][rr];
      }
    sum += __shfl_xor(sum, 16);
    sum += __shfl_xor(sum, 32);
    float inv = 1.f / sum;
    int gp = p >> 3, pl = p & 7;  // gp in {16,17}: unswizzled
#pragma unroll
    for (int mi = 0; mi < 4; ++mi)
#pragma unroll
      for (int rr = 0; rr < 4; ++rr) {
        float a = e[mi][rr] * inv;
        part[mi][rr] += a;
        int k = mi * 16 + hi16 * 4 + rr;
        int idx = k * 144 + (gp << 3) + pl;
        ushort h = bf16rne(a);
        atH[idx] = h;
        atL[idx] = bf16rne(a - bf2f(h));
      }
  }
  // NOTE: old granule-18/19 zero-pad loop removed — it raced with softmax
  // writes of other waves and aliased row k+1 granule 0. Those granules are
  // never read; the dump below writes explicit zeros for the pad column.

  // asum: reduce over l15 then one atomic per k
#pragma unroll
  for (int mi = 0; mi < 4; ++mi)
#pragma unroll
    for (int rr = 0; rr < 4; ++rr) {
      float s = part[mi][rr];
      s += __shfl_xor(s, 1);
      s += __shfl_xor(s, 2);
      s += __shfl_xor(s, 4);
      s += __shfl_xor(s, 8);
      if (l15 == 0) atomicAdd(&asumS[mi * 16 + hi16 * 4 + rr], s);
    }
  __syncthreads();

  // dump a^T UNswizzled + padded: [2][64 rows][19 f4]; c4==18 -> zeros
  {
    float4* dst = aT_ws + (size_t)b * 2432;
    for (int i = t; i < 2432; i += 512) {
      int plane = i / 1216;
      int rem = i - plane * 1216;
      int row = rem / 19, c4 = rem - row * 19;
      float4 v = {0.f, 0.f, 0.f, 0.f};
      if (c4 < 18) {
        int sg = (c4 < 16) ? (c4 ^ (row & 7)) : c4;
        v = *(const float4*)(sm + plane * 18432 + row * 288 + sg * 16);
      }
      dst[i] = v;
    }
    if (t < 64) asum_ws[b * 64 + t] = asumS[t];
  }
}

// ---------------------------------------------------------------------------
// K2: per (n,r,dc of 64): V = X^T * A - C*asum.
// A-frags (x^T) loaded DIRECTLY global->register (transposed addressing via
// LDS poff table, coalesced 64B segments); B-frags (a^T) from linear-copied
// padded-152 LDS. No x LDS staging, no transpose scatter. 512 thr, ~40KB LDS.
// ---------------------------------------------------------------------------
__global__ __launch_bounds__(512) void k2_vlad(
    const float* __restrict__ x, const float* __restrict__ C,
    const float4* __restrict__ aT_ws, const float* __restrict__ asum_ws,
    float* __restrict__ out, float* __restrict__ colnorm) {
  __shared__ float4 smv[2504];               // 40064 B, 16B-aligned
  char* sm = (char*)smv;
  ushort* atH = (ushort*)sm;                 // [64 k][152 p]
  ushort* atL = (ushort*)(sm + 19456);
  int* poff = (int*)(sm + 38912);            // [160] pixel offsets (elements)
  float* asumS = (float*)(sm + 39552);
  float* cn2 = (float*)(sm + 39808);

  int b = blockIdx.x;          // 2304
  int reg = b % 288;           // XCD-swizzle: all 8 dc of a region -> same XCD
  int dc = b / 288;
  int n = reg / 9, r = reg % 9;
  int d0 = dc * 64;
  int y1 = (r / 3) * 12, x1 = (r % 3) * 12;
  int t = threadIdx.x;
  int w = t >> 6, lane = t & 63, l15 = lane & 15, hi16 = lane >> 4;
  const float* xn = x + (size_t)n * (36 * 36 * 512);

  if (t < 160) poff[t] = (t < 144) ? ((y1 + t / 12) * 36 + (x1 + t % 12)) * 512 : 0;
  if (t < 64) {
    asumS[t] = asum_ws[reg * 64 + t];
    cn2[t] = 0.f;
  }
  {
    const float4* src = aT_ws + (size_t)reg * 2432;
    for (int i = t; i < 2432; i += 512) smv[i] = src[i];
  }
  __syncthreads();

  int mi = w & 3, kh = w >> 2;
  int drow = d0 + mi * 16 + l15;
  const float* xcol = xn + drow;

  f32x4 acc[2];
  acc[0] = (f32x4){0.f, 0.f, 0.f, 0.f};
  acc[1] = (f32x4){0.f, 0.f, 0.f, 0.f};

#pragma unroll
  for (int ks = 0; ks < 5; ++ks) {
    int pb = ks * 32 + hi16 * 8;
    int4 poA = *reinterpret_cast<const int4*>(&poff[pb]);
    int4 poB = *reinterpret_cast<const int4*>(&poff[pb + 4]);
    float av[8];
    av[0] = xcol[poA.x]; av[1] = xcol[poA.y];
    av[2] = xcol[poA.z]; av[3] = xcol[poA.w];
    av[4] = xcol[poB.x]; av[5] = xcol[poB.y];
    av[6] = xcol[poB.z]; av[7] = xcol[poB.w];
    bool valid = (ks < 4) || (hi16 < 2);   // p >= 144 -> zero A (kills product)
    short8 ah, al;
#pragma unroll
    for (int j = 0; j < 8; ++j) {
      float v = valid ? av[j] : 0.f;
      ushort h = bf16rne(v);
      ah[j] = (short)h;
      al[j] = (short)bf16rne(v - bf2f(h));
    }
#pragma unroll
    for (int ni = 0; ni < 2; ++ni) {
      int row = kh * 32 + ni * 16 + l15;
      // pb max 152: stays inside LDS (reads pad/garbage only where A==0)
      short8 bh = *(const short8*)(atH + row * 152 + pb);
      short8 bl = *(const short8*)(atL + row * 152 + pb);
      f32x4 a0 = acc[ni];
      a0 = mfma16(ah, bh, a0);
      a0 = mfma16(ah, bl, a0);
      a0 = mfma16(al, bh, a0);
      acc[ni] = a0;
    }
  }

  size_t obase = (size_t)reg * (512 * 64);
#pragma unroll
  for (int ni = 0; ni < 2; ++ni) {
    int k = kh * 32 + ni * 16 + l15;
    float ak = asumS[k];
    float s2 = 0.f;
#pragma unroll
    for (int rr = 0; rr < 4; ++rr) {
      int d = d0 + mi * 16 + hi16 * 4 + rr;
      float v = acc[ni][rr] - C[(size_t)d * 64 + k] * ak;
      out[obase + (size_t)d * 64 + k] = v;
      s2 += v * v;
    }
    atomicAdd(&cn2[k], s2);
  }
  __syncthreads();
  if (t < 64) atomicAdd(&colnorm[reg * 64 + t], cn2[t]);
}

// ---------------------------------------------------------------------------
// K3: intra-norm + global-norm scaling in place.
// ---------------------------------------------------------------------------
__global__ __launch_bounds__(256) void k3_scale(float* __restrict__ out,
                                                const float* __restrict__ colnorm) {
  int b = blockIdx.x;  // 1152
  int reg = b % 288;   // match k2's writer XCD for L2 reuse
  int dc = b / 288;

  __shared__ float ratio[64];
  __shared__ float fs[64];
  int t = threadIdx.x;
  float c = 0.f;
  if (t < 64) {
    c = colnorm[reg * 64 + t];
    ratio[t] = c / (c + EPSF);
  }
  __syncthreads();
  if (t < 64) {
    float g = 0.f;
#pragma unroll
    for (int j = 0; j < 64; ++j) g += ratio[j];
    fs[t] = rsqrtf(c + EPSF) * rsqrtf(g + EPSF);
  }
  __syncthreads();

  size_t base4 = (((size_t)reg * 512) + (size_t)dc * 128) * 64 / 4;
  float4* o4 = reinterpret_cast<float4*>(out);
  for (int j = 0; j < 8; ++j) {
    size_t idx = base4 + t + 256 * j;
    float4 v = o4[idx];
    int k0 = (int)((idx * 4) & 63);
    v.x *= fs[k0]; v.y *= fs[k0 + 1]; v.z *= fs[k0 + 2]; v.w *= fs[k0 + 3];
    o4[idx] = v;
  }
}

extern "C" void kernel_launch(void* const* d_in, const int* in_sizes, int n_in,
                              void* d_out, int out_size, void* d_ws, size_t ws_size,
                              hipStream_t stream) {
  const float* x = (const float*)d_in[0];   // [32,36,36,512]
  const float* Wc = (const float*)d_in[1];  // [512,64]
  const float* C = (const float*)d_in[2];   // [512,64]
  float* out = (float*)d_out;

  char* ws = (char*)d_ws;
  ushort* wsWT = (ushort*)(ws);             // 131072 B
  float* asum_ws = (float*)(ws + 131072);   // 73728 B
  float* colnorm = (float*)(ws + 204800);   // 73728 B
  float4* aT_ws = (float4*)(ws + 278528);   // 288 * 38912 B = 11.2 MB

  hipMemsetAsync(colnorm, 0, 288 * 64 * sizeof(float), stream);
  k0_wt<<<64, 256, 0, stream>>>(Wc, wsWT);
  k1_assign<<<288, 512, 0, stream>>>(x, wsWT, aT_ws, asum_ws);
  k2_vlad<<<2304, 512, 0, stream>>>(x, C, aT_ws, asum_ws, out, colnorm);
  k3_scale<<<1152, 256, 0, stream>>>(out, colnorm);
}

// Round 5
// 80.066 us; speedup vs baseline: 1.9027x; 1.0781x over previous
//
#include <hip/hip_runtime.h>

typedef __attribute__((ext_vector_type(4))) float f32x4;
typedef __attribute__((ext_vector_type(8))) short short8;

#define EPSF 1e-12f

__device__ __forceinline__ ushort bf16rne(float x) {
  uint u = __float_as_uint(x);
  u += 0x7fffu + ((u >> 16) & 1u);
  return (ushort)(u >> 16);
}
__device__ __forceinline__ float bf2f(ushort h) {
  return __uint_as_float(((uint)h) << 16);
}
__device__ __forceinline__ f32x4 mfma16(short8 a, short8 b, f32x4 c) {
  return __builtin_amdgcn_mfma_f32_16x16x32_bf16(a, b, c, 0, 0, 0);
}
// rowlen 64 ushorts (8 granules of 8): XOR-swizzle granule with row&7
__device__ __forceinline__ short8 frag64(const ushort* base, int row, int kofs) {
  int g = kofs >> 3;
  int sg = g ^ (row & 7);
  return *(const short8*)(base + row * 64 + (sg << 3));
}

// ---------------------------------------------------------------------------
// K0: W [512][64] f32 -> W^T bf16 hi/lo in ws: [2][64 k][512 d]
// ---------------------------------------------------------------------------
__global__ __launch_bounds__(256) void k0_wt(const float* __restrict__ W,
                                             ushort* __restrict__ wsWT) {
  int k = blockIdx.x;  // 64
  for (int d = threadIdx.x; d < 512; d += 256) {
    float v = W[(size_t)d * 64 + k];
    ushort h = bf16rne(v);
    wsWT[k * 512 + d] = h;
    wsWT[32768 + k * 512 + d] = bf16rne(v - bf2f(h));
  }
}

// ---------------------------------------------------------------------------
// K1: per (n, r, phalf of 72 pixels): s^T = W^T * x, softmax over k (cross-
// wave LDS reduce), dump a^T granules [2][64 k][9 f4] into the region's
// padded [2][64][19 f4] slot + per-half asum. 256 thr = 4 waves; wave w owns
// mi=w (16 k-rows) x 5 ni (80 p, >=72 garbage-safe). Balanced MFMA.
// ---------------------------------------------------------------------------
__global__ __launch_bounds__(256, 4) void k1_assign(
    const float* __restrict__ x, const ushort* __restrict__ wsWT,
    float4* __restrict__ aT_ws, float* __restrict__ asum_ws) {
  __shared__ char sm[37376];
  ushort* xsH = (ushort*)(sm);            // [72 p][64 d] 9216 B
  ushort* xsL = (ushort*)(sm + 9216);
  ushort* wtH = (ushort*)(sm + 18432);    // [64 k][64 d] 8192 B
  ushort* wtL = (ushort*)(sm + 26624);
  float* smax = (float*)(sm + 34816);     // [4 w][80 p]
  float* ssum = (float*)(sm + 36096);     // [4 w][80 p]
  // overlay after MFMA: a^T [64 k][72 p] u16, hi at 0, lo at 9216
  ushort* atH = (ushort*)(sm);
  ushort* atL = (ushort*)(sm + 9216);

  int b = blockIdx.x;          // 576
  int region = b >> 1, phalf = b & 1;
  int n = region / 9, r = region % 9;
  int y1 = (r / 3) * 12, x1 = (r % 3) * 12;
  int p0 = phalf * 72;
  int t = threadIdx.x;
  int w = t >> 6;
  int lane = t & 63, l15 = lane & 15, hi16 = lane >> 4;
  const float* xn = x + (size_t)n * (36 * 36 * 512);

  float4 px[3][2];
  short8 pwH[2], pwL[2];
  int ntask = (t < 64) ? 3 : 2;   // 576 x-tasks over 256 threads

  f32x4 acc[5];
#pragma unroll
  for (int ni = 0; ni < 5; ++ni) acc[ni] = (f32x4){0.f, 0.f, 0.f, 0.f};

  // -------- prefetch chunk 0 --------
  {
#pragma unroll
    for (int i = 0; i < 3; ++i)
      if (i < ntask) {
        int task = t + i * 256;
        int p = task >> 3, g = task & 7;
        int pr = p0 + p;
        const float* src = xn + ((size_t)(y1 + pr / 12) * 36 + (x1 + pr % 12)) * 512 + g * 8;
        px[i][0] = *(const float4*)src;
        px[i][1] = *(const float4*)(src + 4);
      }
#pragma unroll
    for (int i = 0; i < 2; ++i) {
      int task = t + i * 256;
      int wk = task >> 3, wg = task & 7;
      pwH[i] = *(const short8*)(wsWT + wk * 512 + wg * 8);
      pwL[i] = *(const short8*)(wsWT + 32768 + wk * 512 + wg * 8);
    }
  }

  for (int c = 0; c < 8; ++c) {
    __syncthreads();
    // commit prefetched chunk c
#pragma unroll
    for (int i = 0; i < 3; ++i)
      if (i < ntask) {
        int task = t + i * 256;
        int p = task >> 3, g = task & 7;
        float vals[8] = {px[i][0].x, px[i][0].y, px[i][0].z, px[i][0].w,
                         px[i][1].x, px[i][1].y, px[i][1].z, px[i][1].w};
        short8 h8, l8;
#pragma unroll
        for (int j = 0; j < 8; ++j) {
          ushort h = bf16rne(vals[j]);
          h8[j] = (short)h;
          l8[j] = (short)bf16rne(vals[j] - bf2f(h));
        }
        int sg = g ^ (p & 7);
        *(short8*)(xsH + p * 64 + (sg << 3)) = h8;
        *(short8*)(xsL + p * 64 + (sg << 3)) = l8;
      }
#pragma unroll
    for (int i = 0; i < 2; ++i) {
      int task = t + i * 256;
      int wk = task >> 3, wg = task & 7;
      int sg = wg ^ (wk & 7);
      *(short8*)(wtH + wk * 64 + (sg << 3)) = pwH[i];
      *(short8*)(wtL + wk * 64 + (sg << 3)) = pwL[i];
    }
    // issue prefetch for chunk c+1 (overlaps with MFMA below)
    if (c < 7) {
      int d0 = (c + 1) * 64;
#pragma unroll
      for (int i = 0; i < 3; ++i)
        if (i < ntask) {
          int task = t + i * 256;
          int p = task >> 3, g = task & 7;
          int pr = p0 + p;
          const float* src = xn + ((size_t)(y1 + pr / 12) * 36 + (x1 + pr % 12)) * 512 + d0 + g * 8;
          px[i][0] = *(const float4*)src;
          px[i][1] = *(const float4*)(src + 4);
        }
#pragma unroll
      for (int i = 0; i < 2; ++i) {
        int task = t + i * 256;
        int wk = task >> 3, wg = task & 7;
        pwH[i] = *(const short8*)(wsWT + wk * 512 + d0 + wg * 8);
        pwL[i] = *(const short8*)(wsWT + 32768 + wk * 512 + d0 + wg * 8);
      }
    }
    __syncthreads();

#pragma unroll
    for (int ks = 0; ks < 2; ++ks) {
      int kofs = ks * 32 + hi16 * 8;
      short8 aH = frag64(wtH, w * 16 + l15, kofs);
      short8 aL = frag64(wtL, w * 16 + l15, kofs);
#pragma unroll
      for (int ni = 0; ni < 5; ++ni) {
        // rows >=72 read junk (xsL region) — pollutes only output cols p>=72,
        // which are discarded. In-bounds of LDS.
        short8 bH = frag64(xsH, ni * 16 + l15, kofs);
        short8 bL = frag64(xsL, ni * 16 + l15, kofs);
        f32x4 a0 = acc[ni];
        a0 = mfma16(aH, bH, a0);
        a0 = mfma16(aH, bL, a0);
        a0 = mfma16(aL, bH, a0);
        acc[ni] = a0;
      }
    }
  }
  __syncthreads();  // MFMA reads done; xs becomes a^T overlay

  // ---- softmax over k (cross-wave: each wave holds 16 k's of every p) ----
  // acc[ni][rr] = s[k = w*16 + hi16*4 + rr][p = ni*16 + l15]
  float lm[5];
#pragma unroll
  for (int ni = 0; ni < 5; ++ni) {
    float m = fmaxf(fmaxf(acc[ni][0], acc[ni][1]), fmaxf(acc[ni][2], acc[ni][3]));
    m = fmaxf(m, __shfl_xor(m, 16));
    m = fmaxf(m, __shfl_xor(m, 32));
    lm[ni] = m;  // wave-local max over its 16 k's, per p
  }
  if (hi16 == 0)
#pragma unroll
    for (int ni = 0; ni < 5; ++ni) smax[w * 80 + ni * 16 + l15] = lm[ni];
  __syncthreads();

  float e[5][4], ls[5];
#pragma unroll
  for (int ni = 0; ni < 5; ++ni) {
    int p = ni * 16 + l15;
    float M = fmaxf(fmaxf(smax[0 * 80 + p], smax[1 * 80 + p]),
                    fmaxf(smax[2 * 80 + p], smax[3 * 80 + p]));
    float s = 0.f;
#pragma unroll
    for (int rr = 0; rr < 4; ++rr) {
      e[ni][rr] = __expf(acc[ni][rr] - M);
      s += e[ni][rr];
    }
    s += __shfl_xor(s, 16);
    s += __shfl_xor(s, 32);
    ls[ni] = s;
  }
  if (hi16 == 0)
#pragma unroll
    for (int ni = 0; ni < 5; ++ni) ssum[w * 80 + ni * 16 + l15] = ls[ni];
  __syncthreads();

  float part[4];  // per-thread asum partials for k = w*16 + hi16*4 + rr
#pragma unroll
  for (int rr = 0; rr < 4; ++rr) part[rr] = 0.f;

#pragma unroll
  for (int ni = 0; ni < 5; ++ni) {
    int p = ni * 16 + l15;
    if (p < 72) {
      float S = ssum[0 * 80 + p] + ssum[1 * 80 + p] + ssum[2 * 80 + p] + ssum[3 * 80 + p];
      float inv = 1.f / S;
#pragma unroll
      for (int rr = 0; rr < 4; ++rr) {
        float a = e[ni][rr] * inv;
        part[rr] += a;
        int k = w * 16 + hi16 * 4 + rr;
        ushort h = bf16rne(a);
        atH[k * 72 + p] = h;
        atL[k * 72 + p] = bf16rne(a - bf2f(h));
      }
    }
  }
  // asum reduce over l15 -> slot per (block, k)
#pragma unroll
  for (int rr = 0; rr < 4; ++rr) {
    float s = part[rr];
    s += __shfl_xor(s, 1);
    s += __shfl_xor(s, 2);
    s += __shfl_xor(s, 4);
    s += __shfl_xor(s, 8);
    if (l15 == 0) asum_ws[b * 64 + w * 16 + hi16 * 4 + rr] = s;
  }
  __syncthreads();  // a^T overlay writes done

  // dump a^T to region slot [2][64][19 f4] at granule cols phalf*9..+8
  {
    float4* dst = aT_ws + (size_t)region * 2432;
    for (int i = t; i < 1152; i += 256) {
      int plane = i / 576;
      int rem = i - plane * 576;
      int row = rem / 9, c4 = rem - row * 9;
      float4 v = *(const float4*)(sm + plane * 9216 + row * 144 + c4 * 16);
      dst[plane * 1216 + row * 19 + phalf * 9 + c4] = v;
    }
    if (phalf) {
      float4 z = {0.f, 0.f, 0.f, 0.f};
      for (int i = t; i < 128; i += 256) {
        int plane = i >> 6, row = i & 63;
        dst[plane * 1216 + row * 19 + 18] = z;
      }
    }
  }
}

// ---------------------------------------------------------------------------
// K2: per (n,r,dc of 64): V = X^T * A - C*asum.
// A-frags (x^T) loaded DIRECTLY global->register (transposed addressing via
// LDS poff table); B-frags (a^T) from linear-copied padded-152 LDS.
// colnorm^2 written to a private (reg,dc) slot — no atomics, no memset.
// ---------------------------------------------------------------------------
__global__ __launch_bounds__(512, 8) void k2_vlad(
    const float* __restrict__ x, const float* __restrict__ C,
    const float4* __restrict__ aT_ws, const float* __restrict__ asum_ws,
    float* __restrict__ out, float* __restrict__ colnorm) {
  __shared__ float4 smv[2504];               // 40064 B
  char* sm = (char*)smv;
  ushort* atH = (ushort*)sm;                 // [64 k][152 p]
  ushort* atL = (ushort*)(sm + 19456);
  int* poff = (int*)(sm + 38912);            // [160] pixel offsets (elements)
  float* asumS = (float*)(sm + 39552);
  float* cn2 = (float*)(sm + 39808);

  int b = blockIdx.x;          // 2304
  int reg = b % 288;           // XCD-swizzle: all 8 dc of a region -> same XCD
  int dc = b / 288;
  int n = reg / 9, r = reg % 9;
  int d0 = dc * 64;
  int y1 = (r / 3) * 12, x1 = (r % 3) * 12;
  int t = threadIdx.x;
  int w = t >> 6, lane = t & 63, l15 = lane & 15, hi16 = lane >> 4;
  const float* xn = x + (size_t)n * (36 * 36 * 512);

  if (t < 160) poff[t] = (t < 144) ? ((y1 + t / 12) * 36 + (x1 + t % 12)) * 512 : 0;
  if (t < 64) {
    asumS[t] = asum_ws[(reg * 2) * 64 + t] + asum_ws[(reg * 2 + 1) * 64 + t];
    cn2[t] = 0.f;
  }
  {
    const float4* src = aT_ws + (size_t)reg * 2432;
    for (int i = t; i < 2432; i += 512) smv[i] = src[i];
  }
  __syncthreads();

  int mi = w & 3, kh = w >> 2;
  int drow = d0 + mi * 16 + l15;
  const float* xcol = xn + drow;

  f32x4 acc[2];
  acc[0] = (f32x4){0.f, 0.f, 0.f, 0.f};
  acc[1] = (f32x4){0.f, 0.f, 0.f, 0.f};

#pragma unroll
  for (int ks = 0; ks < 5; ++ks) {
    int pb = ks * 32 + hi16 * 8;
    int4 poA = *reinterpret_cast<const int4*>(&poff[pb]);
    int4 poB = *reinterpret_cast<const int4*>(&poff[pb + 4]);
    float av[8];
    av[0] = xcol[poA.x]; av[1] = xcol[poA.y];
    av[2] = xcol[poA.z]; av[3] = xcol[poA.w];
    av[4] = xcol[poB.x]; av[5] = xcol[poB.y];
    av[6] = xcol[poB.z]; av[7] = xcol[poB.w];
    bool valid = (ks < 4) || (hi16 < 2);   // p >= 144 -> zero A (kills product)
    short8 ah, al;
#pragma unroll
    for (int j = 0; j < 8; ++j) {
      float v = valid ? av[j] : 0.f;
      ushort h = bf16rne(v);
      ah[j] = (short)h;
      al[j] = (short)bf16rne(v - bf2f(h));
    }
#pragma unroll
    for (int ni = 0; ni < 2; ++ni) {
      int row = kh * 32 + ni * 16 + l15;
      short8 bh = *(const short8*)(atH + row * 152 + pb);
      short8 bl = *(const short8*)(atL + row * 152 + pb);
      f32x4 a0 = acc[ni];
      a0 = mfma16(ah, bh, a0);
      a0 = mfma16(ah, bl, a0);
      a0 = mfma16(al, bh, a0);
      acc[ni] = a0;
    }
  }

  size_t obase = (size_t)reg * (512 * 64);
#pragma unroll
  for (int ni = 0; ni < 2; ++ni) {
    int k = kh * 32 + ni * 16 + l15;
    float ak = asumS[k];
    float s2 = 0.f;
#pragma unroll
    for (int rr = 0; rr < 4; ++rr) {
      int d = d0 + mi * 16 + hi16 * 4 + rr;
      float v = acc[ni][rr] - C[(size_t)d * 64 + k] * ak;
      out[obase + (size_t)d * 64 + k] = v;
      s2 += v * v;
    }
    atomicAdd(&cn2[k], s2);
  }
  __syncthreads();
  if (t < 64) colnorm[(size_t)(reg * 8 + dc) * 64 + t] = cn2[t];
}

// ---------------------------------------------------------------------------
// K3: intra-norm + global-norm scaling in place (sums 8 partial colnorms).
// ---------------------------------------------------------------------------
__global__ __launch_bounds__(256) void k3_scale(float* __restrict__ out,
                                                const float* __restrict__ colnorm) {
  int b = blockIdx.x;  // 1152
  int reg = b % 288;   // match k2's writer XCD for L2 reuse
  int dc = b / 288;

  __shared__ float ratio[64];
  __shared__ float fs[64];
  int t = threadIdx.x;
  float c = 0.f;
  if (t < 64) {
#pragma unroll
    for (int j = 0; j < 8; ++j) c += colnorm[(size_t)(reg * 8 + j) * 64 + t];
    ratio[t] = c / (c + EPSF);
  }
  __syncthreads();
  if (t < 64) {
    float g = 0.f;
#pragma unroll
    for (int j = 0; j < 64; ++j) g += ratio[j];
    fs[t] = rsqrtf(c + EPSF) * rsqrtf(g + EPSF);
  }
  __syncthreads();

  size_t base4 = (((size_t)reg * 512) + (size_t)dc * 128) * 64 / 4;
  float4* o4 = reinterpret_cast<float4*>(out);
  for (int j = 0; j < 8; ++j) {
    size_t idx = base4 + t + 256 * j;
    float4 v = o4[idx];
    int k0 = (int)((idx * 4) & 63);
    v.x *= fs[k0]; v.y *= fs[k0 + 1]; v.z *= fs[k0 + 2]; v.w *= fs[k0 + 3];
    o4[idx] = v;
  }
}

extern "C" void kernel_launch(void* const* d_in, const int* in_sizes, int n_in,
                              void* d_out, int out_size, void* d_ws, size_t ws_size,
                              hipStream_t stream) {
  const float* x = (const float*)d_in[0];   // [32,36,36,512]
  const float* Wc = (const float*)d_in[1];  // [512,64]
  const float* C = (const float*)d_in[2];   // [512,64]
  float* out = (float*)d_out;

  char* ws = (char*)d_ws;
  ushort* wsWT = (ushort*)(ws);             // 131072 B
  float* asum_ws = (float*)(ws + 131072);   // 576*64*4 = 147456 B
  float* colnorm = (float*)(ws + 278528);   // 2304*64*4 = 589824 B
  float4* aT_ws = (float4*)(ws + 868352);   // 288 * 38912 B = 11.2 MB

  k0_wt<<<64, 256, 0, stream>>>(Wc, wsWT);
  k1_assign<<<576, 256, 0, stream>>>(x, wsWT, aT_ws, asum_ws);
  k2_vlad<<<2304, 512, 0, stream>>>(x, C, aT_ws, asum_ws, out, colnorm);
  k3_scale<<<1152, 256, 0, stream>>>(out, colnorm);
}

// Round 6
// 78.371 us; speedup vs baseline: 1.9439x; 1.0216x over previous
//
#include <hip/hip_runtime.h>

typedef __attribute__((ext_vector_type(4))) float f32x4;
typedef __attribute__((ext_vector_type(8))) short short8;

#define EPSF 1e-12f

__device__ __forceinline__ ushort bf16rne(float x) {
  uint u = __float_as_uint(x);
  u += 0x7fffu + ((u >> 16) & 1u);
  return (ushort)(u >> 16);
}
__device__ __forceinline__ float bf2f(ushort h) {
  return __uint_as_float(((uint)h) << 16);
}
__device__ __forceinline__ f32x4 mfma16(short8 a, short8 b, f32x4 c) {
  return __builtin_amdgcn_mfma_f32_16x16x32_bf16(a, b, c, 0, 0, 0);
}
// rowlen 64 ushorts (8 granules of 8): XOR-swizzle granule with row&7
__device__ __forceinline__ short8 frag64(const ushort* base, int row, int kofs) {
  int g = kofs >> 3;
  int sg = g ^ (row & 7);
  return *(const short8*)(base + row * 64 + (sg << 3));
}

// ---------------------------------------------------------------------------
// K0: W [512][64] f32 -> W^T bf16 hi/lo in ws: [2][64 k][512 d]
// ---------------------------------------------------------------------------
__global__ __launch_bounds__(256) void k0_wt(const float* __restrict__ W,
                                             ushort* __restrict__ wsWT) {
  int k = blockIdx.x;  // 64
  for (int d = threadIdx.x; d < 512; d += 256) {
    float v = W[(size_t)d * 64 + k];
    ushort h = bf16rne(v);
    wsWT[k * 512 + d] = h;
    wsWT[32768 + k * 512 + d] = bf16rne(v - bf2f(h));
  }
}

// ---------------------------------------------------------------------------
// K1: per (n, r, third of 48 pixels): s^T = W^T * x, softmax over k (cross-
// wave LDS reduce), dump a^T granules [2][64 k][6 f4] into the region's
// padded [2][64][19 f4] slot + per-third asum.
// 256 thr = 4 waves; wave w owns mi=w (16 k-rows) x 3 ni (48 p exact).
// 864 blocks -> 5 blocks/CU (29.5 KB LDS), reg-prefetch double-buffer.
// ---------------------------------------------------------------------------
__global__ __launch_bounds__(256, 5) void k1_assign(
    const float* __restrict__ x, const ushort* __restrict__ wsWT,
    float4* __restrict__ aT_ws, float* __restrict__ asum_ws) {
  __shared__ char sm[30208];
  ushort* xsH = (ushort*)(sm);            // [48 p][64 d] 6144 B
  ushort* xsL = (ushort*)(sm + 6144);
  ushort* wtH = (ushort*)(sm + 12288);    // [64 k][64 d] 8192 B
  ushort* wtL = (ushort*)(sm + 20480);
  float* smax = (float*)(sm + 28672);     // [4 w][48 p]
  float* ssum = (float*)(sm + 29440);     // [4 w][48 p]
  // overlay after all MFMA: a^T [64 k][56-pad p] u16; hi at 0, lo at 7168
  // (atL spills 2KB into wtH region — dead by then, separated by a barrier)
  ushort* atH = (ushort*)(sm);
  ushort* atL = (ushort*)(sm + 7168);

  int b = blockIdx.x;          // 864
  int region = b / 3, third = b % 3;
  int n = region / 9, r = region % 9;
  int y1 = (r / 3) * 12, x1 = (r % 3) * 12;
  int p0 = third * 48;
  int t = threadIdx.x;
  int w = t >> 6;
  int lane = t & 63, l15 = lane & 15, hi16 = lane >> 4;
  const float* xn = x + (size_t)n * (36 * 36 * 512);

  float4 px[2][2];
  short8 pwH[2], pwL[2];
  int ntask = (t < 128) ? 2 : 1;   // 384 x-tasks over 256 threads

  f32x4 acc[3];
#pragma unroll
  for (int ni = 0; ni < 3; ++ni) acc[ni] = (f32x4){0.f, 0.f, 0.f, 0.f};

  // -------- prefetch chunk 0 --------
  {
#pragma unroll
    for (int i = 0; i < 2; ++i)
      if (i < ntask) {
        int task = t + i * 256;
        int p = task >> 3, g = task & 7;
        int pr = p0 + p;
        const float* src = xn + ((size_t)(y1 + pr / 12) * 36 + (x1 + pr % 12)) * 512 + g * 8;
        px[i][0] = *(const float4*)src;
        px[i][1] = *(const float4*)(src + 4);
      }
#pragma unroll
    for (int i = 0; i < 2; ++i) {
      int task = t + i * 256;
      int wk = task >> 3, wg = task & 7;
      pwH[i] = *(const short8*)(wsWT + wk * 512 + wg * 8);
      pwL[i] = *(const short8*)(wsWT + 32768 + wk * 512 + wg * 8);
    }
  }

  for (int c = 0; c < 8; ++c) {
    __syncthreads();
    // commit prefetched chunk c
#pragma unroll
    for (int i = 0; i < 2; ++i)
      if (i < ntask) {
        int task = t + i * 256;
        int p = task >> 3, g = task & 7;
        float vals[8] = {px[i][0].x, px[i][0].y, px[i][0].z, px[i][0].w,
                         px[i][1].x, px[i][1].y, px[i][1].z, px[i][1].w};
        short8 h8, l8;
#pragma unroll
        for (int j = 0; j < 8; ++j) {
          ushort h = bf16rne(vals[j]);
          h8[j] = (short)h;
          l8[j] = (short)bf16rne(vals[j] - bf2f(h));
        }
        int sg = g ^ (p & 7);
        *(short8*)(xsH + p * 64 + (sg << 3)) = h8;
        *(short8*)(xsL + p * 64 + (sg << 3)) = l8;
      }
#pragma unroll
    for (int i = 0; i < 2; ++i) {
      int task = t + i * 256;
      int wk = task >> 3, wg = task & 7;
      int sg = wg ^ (wk & 7);
      *(short8*)(wtH + wk * 64 + (sg << 3)) = pwH[i];
      *(short8*)(wtL + wk * 64 + (sg << 3)) = pwL[i];
    }
    // issue prefetch for chunk c+1 (overlaps with MFMA below)
    if (c < 7) {
      int d0 = (c + 1) * 64;
#pragma unroll
      for (int i = 0; i < 2; ++i)
        if (i < ntask) {
          int task = t + i * 256;
          int p = task >> 3, g = task & 7;
          int pr = p0 + p;
          const float* src = xn + ((size_t)(y1 + pr / 12) * 36 + (x1 + pr % 12)) * 512 + d0 + g * 8;
          px[i][0] = *(const float4*)src;
          px[i][1] = *(const float4*)(src + 4);
        }
#pragma unroll
      for (int i = 0; i < 2; ++i) {
        int task = t + i * 256;
        int wk = task >> 3, wg = task & 7;
        pwH[i] = *(const short8*)(wsWT + wk * 512 + d0 + wg * 8);
        pwL[i] = *(const short8*)(wsWT + 32768 + wk * 512 + d0 + wg * 8);
      }
    }
    __syncthreads();

#pragma unroll
    for (int ks = 0; ks < 2; ++ks) {
      int kofs = ks * 32 + hi16 * 8;
      short8 aH = frag64(wtH, w * 16 + l15, kofs);
      short8 aL = frag64(wtL, w * 16 + l15, kofs);
#pragma unroll
      for (int ni = 0; ni < 3; ++ni) {
        short8 bH = frag64(xsH, ni * 16 + l15, kofs);
        short8 bL = frag64(xsL, ni * 16 + l15, kofs);
        f32x4 a0 = acc[ni];
        a0 = mfma16(aH, bH, a0);
        a0 = mfma16(aH, bL, a0);
        a0 = mfma16(aL, bH, a0);
        acc[ni] = a0;
      }
    }
  }
  __syncthreads();  // MFMA reads done; xs/wt become a^T overlay

  // ---- softmax over k (cross-wave: each wave holds 16 k's of every p) ----
  // acc[ni][rr] = s[k = w*16 + hi16*4 + rr][p = ni*16 + l15]
  float lm[3];
#pragma unroll
  for (int ni = 0; ni < 3; ++ni) {
    float m = fmaxf(fmaxf(acc[ni][0], acc[ni][1]), fmaxf(acc[ni][2], acc[ni][3]));
    m = fmaxf(m, __shfl_xor(m, 16));
    m = fmaxf(m, __shfl_xor(m, 32));
    lm[ni] = m;  // wave-local max over its 16 k's, per p
  }
  if (hi16 == 0)
#pragma unroll
    for (int ni = 0; ni < 3; ++ni) smax[w * 48 + ni * 16 + l15] = lm[ni];
  __syncthreads();

  float e[3][4], ls[3];
#pragma unroll
  for (int ni = 0; ni < 3; ++ni) {
    int p = ni * 16 + l15;
    float M = fmaxf(fmaxf(smax[0 * 48 + p], smax[1 * 48 + p]),
                    fmaxf(smax[2 * 48 + p], smax[3 * 48 + p]));
    float s = 0.f;
#pragma unroll
    for (int rr = 0; rr < 4; ++rr) {
      e[ni][rr] = __expf(acc[ni][rr] - M);
      s += e[ni][rr];
    }
    s += __shfl_xor(s, 16);
    s += __shfl_xor(s, 32);
    ls[ni] = s;
  }
  if (hi16 == 0)
#pragma unroll
    for (int ni = 0; ni < 3; ++ni) ssum[w * 48 + ni * 16 + l15] = ls[ni];
  __syncthreads();

  float part[4];  // per-thread asum partials for k = w*16 + hi16*4 + rr
#pragma unroll
  for (int rr = 0; rr < 4; ++rr) part[rr] = 0.f;

#pragma unroll
  for (int ni = 0; ni < 3; ++ni) {
    int p = ni * 16 + l15;
    float S = ssum[0 * 48 + p] + ssum[1 * 48 + p] + ssum[2 * 48 + p] + ssum[3 * 48 + p];
    float inv = 1.f / S;
#pragma unroll
    for (int rr = 0; rr < 4; ++rr) {
      float a = e[ni][rr] * inv;
      part[rr] += a;
      int k = w * 16 + hi16 * 4 + rr;
      ushort h = bf16rne(a);
      atH[k * 56 + p] = h;
      atL[k * 56 + p] = bf16rne(a - bf2f(h));
    }
  }
  // asum reduce over l15 -> slot per (block, k)
#pragma unroll
  for (int rr = 0; rr < 4; ++rr) {
    float s = part[rr];
    s += __shfl_xor(s, 1);
    s += __shfl_xor(s, 2);
    s += __shfl_xor(s, 4);
    s += __shfl_xor(s, 8);
    if (l15 == 0) asum_ws[b * 64 + w * 16 + hi16 * 4 + rr] = s;
  }
  __syncthreads();  // a^T overlay writes done

  // dump a^T to region slot [2][64][19 f4] at granule cols third*6..+5
  {
    float4* dst = aT_ws + (size_t)region * 2432;
    for (int i = t; i < 768; i += 256) {
      int plane = i / 384;
      int rem = i - plane * 384;
      int row = rem / 6, c4 = rem - row * 6;
      float4 v = *(const float4*)(sm + plane * 7168 + row * 112 + c4 * 16);
      dst[plane * 1216 + row * 19 + third * 6 + c4] = v;
    }
    if (third == 2) {
      float4 z = {0.f, 0.f, 0.f, 0.f};
      for (int i = t; i < 128; i += 256) {
        int plane = i >> 6, row = i & 63;
        dst[plane * 1216 + row * 19 + 18] = z;
      }
    }
  }
}

// ---------------------------------------------------------------------------
// K2: per (n,r,dc of 64): V = X^T * A - C*asum.
// A-frags (x^T) loaded DIRECTLY global->register (transposed addressing via
// LDS poff table); B-frags (a^T) from linear-copied padded-152 LDS.
// colnorm^2 written to a private (reg,dc) slot — no atomics, no memset.
// ---------------------------------------------------------------------------
__global__ __launch_bounds__(512, 8) void k2_vlad(
    const float* __restrict__ x, const float* __restrict__ C,
    const float4* __restrict__ aT_ws, const float* __restrict__ asum_ws,
    float* __restrict__ out, float* __restrict__ colnorm) {
  __shared__ float4 smv[2504];               // 40064 B
  char* sm = (char*)smv;
  ushort* atH = (ushort*)sm;                 // [64 k][152 p]
  ushort* atL = (ushort*)(sm + 19456);
  int* poff = (int*)(sm + 38912);            // [160] pixel offsets (elements)
  float* asumS = (float*)(sm + 39552);
  float* cn2 = (float*)(sm + 39808);

  int b = blockIdx.x;          // 2304
  int reg = b % 288;           // XCD-swizzle: all 8 dc of a region -> same XCD
  int dc = b / 288;
  int n = reg / 9, r = reg % 9;
  int d0 = dc * 64;
  int y1 = (r / 3) * 12, x1 = (r % 3) * 12;
  int t = threadIdx.x;
  int w = t >> 6, lane = t & 63, l15 = lane & 15, hi16 = lane >> 4;
  const float* xn = x + (size_t)n * (36 * 36 * 512);

  if (t < 160) poff[t] = (t < 144) ? ((y1 + t / 12) * 36 + (x1 + t % 12)) * 512 : 0;
  if (t < 64) {
    asumS[t] = asum_ws[(reg * 3) * 64 + t] + asum_ws[(reg * 3 + 1) * 64 + t] +
               asum_ws[(reg * 3 + 2) * 64 + t];
    cn2[t] = 0.f;
  }
  {
    const float4* src = aT_ws + (size_t)reg * 2432;
    for (int i = t; i < 2432; i += 512) smv[i] = src[i];
  }
  __syncthreads();

  int mi = w & 3, kh = w >> 2;
  int drow = d0 + mi * 16 + l15;
  const float* xcol = xn + drow;

  f32x4 acc[2];
  acc[0] = (f32x4){0.f, 0.f, 0.f, 0.f};
  acc[1] = (f32x4){0.f, 0.f, 0.f, 0.f};

#pragma unroll
  for (int ks = 0; ks < 5; ++ks) {
    int pb = ks * 32 + hi16 * 8;
    int4 poA = *reinterpret_cast<const int4*>(&poff[pb]);
    int4 poB = *reinterpret_cast<const int4*>(&poff[pb + 4]);
    float av[8];
    av[0] = xcol[poA.x]; av[1] = xcol[poA.y];
    av[2] = xcol[poA.z]; av[3] = xcol[poA.w];
    av[4] = xcol[poB.x]; av[5] = xcol[poB.y];
    av[6] = xcol[poB.z]; av[7] = xcol[poB.w];
    bool valid = (ks < 4) || (hi16 < 2);   // p >= 144 -> zero A (kills product)
    short8 ah, al;
#pragma unroll
    for (int j = 0; j < 8; ++j) {
      float v = valid ? av[j] : 0.f;
      ushort h = bf16rne(v);
      ah[j] = (short)h;
      al[j] = (short)bf16rne(v - bf2f(h));
    }
#pragma unroll
    for (int ni = 0; ni < 2; ++ni) {
      int row = kh * 32 + ni * 16 + l15;
      short8 bh = *(const short8*)(atH + row * 152 + pb);
      short8 bl = *(const short8*)(atL + row * 152 + pb);
      f32x4 a0 = acc[ni];
      a0 = mfma16(ah, bh, a0);
      a0 = mfma16(ah, bl, a0);
      a0 = mfma16(al, bh, a0);
      acc[ni] = a0;
    }
  }

  size_t obase = (size_t)reg * (512 * 64);
#pragma unroll
  for (int ni = 0; ni < 2; ++ni) {
    int k = kh * 32 + ni * 16 + l15;
    float ak = asumS[k];
    float s2 = 0.f;
#pragma unroll
    for (int rr = 0; rr < 4; ++rr) {
      int d = d0 + mi * 16 + hi16 * 4 + rr;
      float v = acc[ni][rr] - C[(size_t)d * 64 + k] * ak;
      out[obase + (size_t)d * 64 + k] = v;
      s2 += v * v;
    }
    atomicAdd(&cn2[k], s2);
  }
  __syncthreads();
  if (t < 64) colnorm[(size_t)(reg * 8 + dc) * 64 + t] = cn2[t];
}

// ---------------------------------------------------------------------------
// K3: intra-norm + global-norm scaling in place (sums 8 partial colnorms).
// ---------------------------------------------------------------------------
__global__ __launch_bounds__(256) void k3_scale(float* __restrict__ out,
                                                const float* __restrict__ colnorm) {
  int b = blockIdx.x;  // 1152
  int reg = b % 288;   // match k2's writer XCD for L2 reuse
  int dc = b / 288;

  __shared__ float ratio[64];
  __shared__ float fs[64];
  int t = threadIdx.x;
  float c = 0.f;
  if (t < 64) {
#pragma unroll
    for (int j = 0; j < 8; ++j) c += colnorm[(size_t)(reg * 8 + j) * 64 + t];
    ratio[t] = c / (c + EPSF);
  }
  __syncthreads();
  if (t < 64) {
    float g = 0.f;
#pragma unroll
    for (int j = 0; j < 64; ++j) g += ratio[j];
    fs[t] = rsqrtf(c + EPSF) * rsqrtf(g + EPSF);
  }
  __syncthreads();

  size_t base4 = (((size_t)reg * 512) + (size_t)dc * 128) * 64 / 4;
  float4* o4 = reinterpret_cast<float4*>(out);
  for (int j = 0; j < 8; ++j) {
    size_t idx = base4 + t + 256 * j;
    float4 v = o4[idx];
    int k0 = (int)((idx * 4) & 63);
    v.x *= fs[k0]; v.y *= fs[k0 + 1]; v.z *= fs[k0 + 2]; v.w *= fs[k0 + 3];
    o4[idx] = v;
  }
}

extern "C" void kernel_launch(void* const* d_in, const int* in_sizes, int n_in,
                              void* d_out, int out_size, void* d_ws, size_t ws_size,
                              hipStream_t stream) {
  const float* x = (const float*)d_in[0];   // [32,36,36,512]
  const float* Wc = (const float*)d_in[1];  // [512,64]
  const float* C = (const float*)d_in[2];   // [512,64]
  float* out = (float*)d_out;

  char* ws = (char*)d_ws;
  ushort* wsWT = (ushort*)(ws);             // 131072 B
  float* asum_ws = (float*)(ws + 131072);   // 864*64*4 = 221184 B
  float* colnorm = (float*)(ws + 352256);   // 2304*64*4 = 589824 B
  float4* aT_ws = (float4*)(ws + 942080);   // 288 * 38912 B = 11.2 MB

  k0_wt<<<64, 256, 0, stream>>>(Wc, wsWT);
  k1_assign<<<864, 256, 0, stream>>>(x, wsWT, aT_ws, asum_ws);
  k2_vlad<<<2304, 512, 0, stream>>>(x, C, aT_ws, asum_ws, out, colnorm);
  k3_scale<<<1152, 256, 0, stream>>>(out, colnorm);
}